// Round 5
// baseline (1408.389 us; speedup 1.0000x reference)
//
#include <hip/hip_runtime.h>
#include <math.h>

#define NEG_INF (-__builtin_inff())

__device__ __forceinline__ float silu_f(float y) {
    return y / (1.f + __expf(-y));
}

// ---------------- CSR build ----------------

__global__ void k_count(const int* __restrict__ ei, int* __restrict__ cnt, int E) {
    int e = blockIdx.x * 256 + threadIdx.x;
    if (e < E) atomicAdd(&cnt[ei[E + e]], 1);
}

__global__ void k_scanA(const int* __restrict__ cnt, int* __restrict__ bsum, int N) {
    __shared__ int sh[4];
    int i = blockIdx.x * 256 + threadIdx.x;
    int v = (i < N) ? cnt[i] : 0;
#pragma unroll
    for (int m = 1; m < 64; m <<= 1) v += __shfl_xor(v, m, 64);
    int w = threadIdx.x >> 6;
    if ((threadIdx.x & 63) == 0) sh[w] = v;
    __syncthreads();
    if (threadIdx.x == 0) bsum[blockIdx.x] = sh[0] + sh[1] + sh[2] + sh[3];
}

__global__ void k_scanB(const int* __restrict__ bsum, int* __restrict__ boff,
                        int* __restrict__ off, int nb, int N) {
    int lane = threadIdx.x & 63;
    int run = 0;
    for (int base = 0; base < nb; base += 64) {
        int i = base + lane;
        int ov = (i < nb) ? bsum[i] : 0;
        int v = ov;
#pragma unroll
        for (int s = 1; s < 64; s <<= 1) {
            int q = __shfl_up(v, s, 64);
            if (lane >= s) v += q;
        }
        if (i < nb) boff[i] = run + v - ov;
        run += __shfl(v, 63, 64);
    }
    if (lane == 0) off[N] = run;
}

__global__ void k_scanC(const int* __restrict__ cnt, const int* __restrict__ boff,
                        int* __restrict__ off, int N) {
    __shared__ int ls[256];
    int t = threadIdx.x;
    int i = blockIdx.x * 256 + t;
    int myv = (i < N) ? cnt[i] : 0;
    ls[t] = myv;
    __syncthreads();
#pragma unroll
    for (int s = 1; s < 256; s <<= 1) {
        int add = (t >= s) ? ls[t - s] : 0;
        __syncthreads();
        ls[t] += add;
        __syncthreads();
    }
    if (i < N) off[i] = boff[blockIdx.x] + ls[t] - myv;
}

__global__ void k_fill(const int* __restrict__ ei, const int* __restrict__ off,
                       int* __restrict__ cur, int* __restrict__ csr, int E) {
    int e = blockIdx.x * 256 + threadIdx.x;
    if (e < E) {
        int d = ei[E + e];
        int pos = off[d] + atomicAdd(&cur[d], 1);
        csr[pos] = ei[e];
    }
}

// ---------------- Prep: transposed / folded MLP weights ----------------
// w1t[j][c] = mlp_W1[c][j];  g2[j][o] = mlp_g[j]*mlp_W2[j][o]
// k12[o] = sum_j bn_j*W2[j][o] + b2[o];  k12[64+o] = sum_j g_j*W2[j][o]

__global__ void k_prep(const float* __restrict__ mW1, const float* __restrict__ mg,
                       const float* __restrict__ mbn, const float* __restrict__ mW2,
                       const float* __restrict__ mb2,
                       float* __restrict__ w1t, float* __restrict__ g2,
                       float* __restrict__ k12)
{
    int b = blockIdx.x, t = threadIdx.x;
    if (b == 0) {
        for (int c = 0; c < 64; ++c) w1t[t * 64 + c] = mW1[c * 256 + t];
    } else if (b == 1 || b == 2) {
        int base = (b - 1) * 8192;
        for (int i = base + t; i < base + 8192; i += 256)
            g2[i] = mg[i >> 6] * mW2[i];
    } else if (b == 3 && t < 64) {
        float a1 = 0.f, a2 = 0.f;
        for (int j = 0; j < 256; ++j) {
            a1 += mbn[j] * mW2[j * 64 + t];
            a2 += mg[j]  * mW2[j * 64 + t];
        }
        k12[t] = a1 + mb2[t];
        k12[64 + t] = a2;
    }
}

// ---------------- Layer 0 (N_IN=4), one thread per node ----------------

__global__ __launch_bounds__(256, 4)
void k_layer0(const float* __restrict__ x, float* __restrict__ hout,
              const int* __restrict__ off, const int* __restrict__ csr,
              const float* __restrict__ Wl0, const float* __restrict__ bl0,
              const float* __restrict__ Wr0, const float* __restrict__ Wres,
              const float* __restrict__ bres, const float* __restrict__ lg,
              const float* __restrict__ lb, int N)
{
    __shared__ float sWl[512], sWr[256], sWres[256], sC[256];
    int t = threadIdx.x;
    sWl[t] = Wl0[t]; sWl[256 + t] = Wl0[256 + t];
    sWr[t] = Wr0[t];
    sWres[t] = Wres[t];
    if (t < 64) { sC[t] = bl0[t]; sC[64 + t] = bres[t]; sC[128 + t] = lg[t]; sC[192 + t] = lb[t]; }
    __syncthreads();
    int v = blockIdx.x * 256 + t;
    if (v >= N) return;
    const float4* X4 = reinterpret_cast<const float4*>(x);
    float4 xv = X4[v];
    int s0 = off[v], s1 = off[v + 1];
    float4 mx = {NEG_INF, NEG_INF, NEG_INF, NEG_INF};
    float4 sm = {0.f, 0.f, 0.f, 0.f};
    for (int e = s0; e < s1; e += 4) {
        int last = s1 - 1;
        int i0 = csr[e];
        int i1 = csr[min(e + 1, last)];
        int i2 = csr[min(e + 2, last)];
        int i3 = csr[min(e + 3, last)];
        float4 a0 = X4[i0], a1 = X4[i1], a2 = X4[i2], a3 = X4[i3];
        mx.x = fmaxf(fmaxf(fmaxf(mx.x, a0.x), fmaxf(a1.x, a2.x)), a3.x);
        mx.y = fmaxf(fmaxf(fmaxf(mx.y, a0.y), fmaxf(a1.y, a2.y)), a3.y);
        mx.z = fmaxf(fmaxf(fmaxf(mx.z, a0.z), fmaxf(a1.z, a2.z)), a3.z);
        mx.w = fmaxf(fmaxf(fmaxf(mx.w, a0.w), fmaxf(a1.w, a2.w)), a3.w);
        bool o1 = e + 1 < s1, o2 = e + 2 < s1, o3 = e + 3 < s1;
        sm.x += a0.x + (o1 ? a1.x : 0.f) + (o2 ? a2.x : 0.f) + (o3 ? a3.x : 0.f);
        sm.y += a0.y + (o1 ? a1.y : 0.f) + (o2 ? a2.y : 0.f) + (o3 ? a3.y : 0.f);
        sm.z += a0.z + (o1 ? a1.z : 0.f) + (o2 ? a2.z : 0.f) + (o3 ? a3.z : 0.f);
        sm.w += a0.w + (o1 ? a1.w : 0.f) + (o2 ? a2.w : 0.f) + (o3 ? a3.w : 0.f);
    }
    int deg = s1 - s0;
    if (deg == 0) { mx.x = 0.f; mx.y = 0.f; mx.z = 0.f; mx.w = 0.f; }
    float inv = 1.f / (float)max(deg, 1);
    float4 mn = {sm.x * inv, sm.y * inv, sm.z * inv, sm.w * inv};
    float a[64];
    float acc1 = 0.f, acc2 = 0.f;
#pragma unroll
    for (int k = 0; k < 64; ++k) {
        float tv = sC[k]
            + mx.x * sWl[k]       + mx.y * sWl[64 + k]  + mx.z * sWl[128 + k] + mx.w * sWl[192 + k]
            + mn.x * sWl[256 + k] + mn.y * sWl[320 + k] + mn.z * sWl[384 + k] + mn.w * sWl[448 + k]
            + xv.x * sWr[k]       + xv.y * sWr[64 + k]  + xv.z * sWr[128 + k] + xv.w * sWr[192 + k];
        a[k] = tv; acc1 += tv; acc2 += tv * tv;
    }
    float mu = acc1 * (1.f / 64.f);
    float var = acc2 * (1.f / 64.f) - mu * mu;
    float rs = rsqrtf(var + 1e-5f);
    float* orow = hout + (size_t)v * 64;
#pragma unroll
    for (int k = 0; k < 64; ++k) {
        float res = sC[64 + k] + xv.x * sWres[k] + xv.y * sWres[64 + k]
                  + xv.z * sWres[128 + k] + xv.w * sWres[192 + k];
        float y = (a[k] - mu) * rs * sC[128 + k] + sC[192 + k] + res;
        orow[k] = silu_f(y);
    }
}

// ---------------- k_agg: gather + aggregate only (high occupancy) ----------------
// writes aggws[node][0..63]=max, [64..127]=mean

__global__ __launch_bounds__(256, 8)
void k_agg(const float* __restrict__ hin, float* __restrict__ aggws,
           const int* __restrict__ off, const int* __restrict__ csr, int N)
{
    int lane = threadIdx.x & 63;
    int gw = (blockIdx.x * blockDim.x + threadIdx.x) >> 6;
    int nw = (gridDim.x * blockDim.x) >> 6;
    for (int v = gw; v < N; v += nw) {
        int s0 = off[v], s1 = off[v + 1];
        float mx = NEG_INF, sm = 0.f;
        for (int cb = s0; cb < s1; cb += 64) {
            int cdeg = min(64, s1 - cb);
            int idxv = csr[min(cb + lane, s1 - 1)];
            for (int b = 0; b < cdeg; b += 8) {
                float vv[8];
#pragma unroll
                for (int u = 0; u < 8; ++u) {
                    int iu = __builtin_amdgcn_readlane(idxv, b + u);
                    vv[u] = hin[((size_t)iu << 6) + lane];
                }
#pragma unroll
                for (int u = 0; u < 8; ++u) {
                    mx = fmaxf(mx, vv[u]);                // dup rows don't change max
                    sm += (b + u < cdeg) ? vv[u] : 0.f;   // mask dups out of sum
                }
            }
        }
        int deg = s1 - s0;
        if (deg == 0) mx = 0.f;
        float mean = sm / (float)max(deg, 1);
        aggws[((size_t)v << 7) + lane] = mx;
        aggws[((size_t)v << 7) + 64 + lane] = mean;
    }
}

// ---------------- k_smm: matmul+LN+silu; inputs via s_load (wave-uniform rows) ----------------
// lane = output channel; weights in VGPR arrays; the broadcast operand comes
// from SGPRs (readfirstlane-forced uniform row pointers), 1 VALU per MAC.

__global__ __launch_bounds__(256, 2)
void k_smm(const float* __restrict__ aggws, const float* __restrict__ hin,
           float* __restrict__ hout,
           const float* __restrict__ Wl, const float* __restrict__ bl,
           const float* __restrict__ Wr, const float* __restrict__ lg,
           const float* __restrict__ lb, int N)
{
    int lane = threadIdx.x & 63;
    int gw = (blockIdx.x * blockDim.x + threadIdx.x) >> 6;
    int nw = (gridDim.x * blockDim.x) >> 6;
    float wl[128], wr[64];
#pragma unroll
    for (int c = 0; c < 128; ++c) wl[c] = Wl[c * 64 + lane];
#pragma unroll
    for (int c = 0; c < 64; ++c) wr[c] = Wr[c * 64 + lane];
    float blv = bl[lane], gv = lg[lane], bv = lb[lane];
    for (int v = gw; v < N; v += nw) {
        int vu = __builtin_amdgcn_readfirstlane(v);       // force wave-uniform
        const float* __restrict__ ar = aggws + ((size_t)vu << 7);   // s_load source
        const float* __restrict__ hr = hin + ((size_t)vu << 6);     // s_load source
        float hs = hr[lane];                               // per-lane vmem (residual)
        float a0 = blv, a1 = 0.f, a2 = 0.f;
#pragma unroll
        for (int c = 0; c < 64; ++c) {
            a0 += ar[c] * wl[c];            // s * v -> v_fmac
            a1 += ar[64 + c] * wl[64 + c];
            a2 += hr[c] * wr[c];
        }
        float acc = a0 + a1 + a2;
        float mu = acc;
#pragma unroll
        for (int m = 1; m < 64; m <<= 1) mu += __shfl_xor(mu, m, 64);
        mu *= (1.f / 64.f);
        float xc = acc - mu;
        float var = xc * xc;
#pragma unroll
        for (int m = 1; m < 64; m <<= 1) var += __shfl_xor(var, m, 64);
        var *= (1.f / 64.f);
        float y = xc * rsqrtf(var + 1e-5f) * gv + bv + hs;
        hout[((size_t)vu << 6) + lane] = silu_f(y);
    }
}

// ---------------- k_mlp: transposed (lane = node), weights streamed as scalars ----------------
// s_j = silu(h . W1t[j] + b1[j]); A[o] += s_j * g2[j][o];
// out[o] = rs*A[o] + K1[o] - rs*mu*K2[o]
// 64-thread blocks + min-1-wave bound: full VGPR budget for h[64]+A[64].

__global__ __launch_bounds__(64, 1)
void k_mlp(const float* __restrict__ hin, float* __restrict__ hout,
           const float* __restrict__ W1t, const float* __restrict__ b1,
           const float* __restrict__ G2, const float* __restrict__ K12, int N)
{
    int lane = threadIdx.x;
    int node = blockIdx.x * 64 + lane;
    int nclamp = min(node, N - 1);

    float h[64];
    {
        const float4* hrow = reinterpret_cast<const float4*>(hin + ((size_t)nclamp << 6));
#pragma unroll
        for (int k = 0; k < 16; ++k) {
            float4 t4 = hrow[k];
            h[4 * k] = t4.x; h[4 * k + 1] = t4.y; h[4 * k + 2] = t4.z; h[4 * k + 3] = t4.w;
        }
    }
    float A[64];
#pragma unroll
    for (int o = 0; o < 64; ++o) A[o] = 0.f;
    float acc1 = 0.f, acc2 = 0.f;
    for (int j = 0; j < 256; ++j) {
        const float* __restrict__ w1 = W1t + (j << 6);   // uniform -> s_load
        const float* __restrict__ g2 = G2 + (j << 6);    // uniform -> s_load
        float t0 = b1[j], t1 = 0.f, t2 = 0.f, t3 = 0.f;
#pragma unroll
        for (int c = 0; c < 64; c += 4) {
            t0 += h[c] * w1[c];
            t1 += h[c + 1] * w1[c + 1];
            t2 += h[c + 2] * w1[c + 2];
            t3 += h[c + 3] * w1[c + 3];
        }
        float s = silu_f((t0 + t1) + (t2 + t3));
        acc1 += s; acc2 += s * s;
#pragma unroll
        for (int o = 0; o < 64; ++o) A[o] += s * g2[o];
    }
    float mu = acc1 * (1.f / 256.f);
    float var = acc2 * (1.f / 256.f) - mu * mu;
    float rs = rsqrtf(var + 1e-5f);
    float rm = rs * mu;
    bool alive = node < N;
    float* orow = hout + ((size_t)node << 6);
#pragma unroll
    for (int k = 0; k < 16; ++k) {
        float4 yv;
        yv.x = rs * A[4 * k]     + K12[4 * k]     - rm * K12[64 + 4 * k];
        yv.y = rs * A[4 * k + 1] + K12[4 * k + 1] - rm * K12[64 + 4 * k + 1];
        yv.z = rs * A[4 * k + 2] + K12[4 * k + 2] - rm * K12[64 + 4 * k + 2];
        yv.w = rs * A[4 * k + 3] + K12[4 * k + 3] - rm * K12[64 + 4 * k + 3];
        if (alive) *reinterpret_cast<float4*>(&orow[4 * k]) = yv;
    }
}

// ---------------- Readout: block per graph ----------------

__global__ __launch_bounds__(256, 2)
void k_readout(const float* __restrict__ h2, const float* __restrict__ x,
               const int* __restrict__ ptr,
               const float* __restrict__ W1, const float* __restrict__ b1,
               const float* __restrict__ lg, const float* __restrict__ lb,
               const float* __restrict__ W2, const float* __restrict__ b2,
               float* __restrict__ out)
{
    __shared__ float f[196];
    __shared__ float sred[4][64];
    __shared__ float mred[4][64];
    __shared__ float lred[8];
    __shared__ float pr[4][4];
    int t = threadIdx.x, lane = t & 63, w = t >> 6;
    int g = blockIdx.x;
    int s0 = ptr[g], s1 = ptr[g + 1];
    float sm = 0.f, mx = NEG_INF;
    for (int r = s0 + w; r < s1; r += 4) {
        float v = h2[(size_t)r * 64 + lane];
        sm += v; mx = fmaxf(mx, v);
    }
    sred[w][lane] = sm; mred[w][lane] = mx;
    __syncthreads();
    if (w == 0) {
        float ssum = sred[0][lane] + sred[1][lane] + sred[2][lane] + sred[3][lane];
        float smax = fmaxf(fmaxf(mred[0][lane], mred[1][lane]),
                           fmaxf(mred[2][lane], mred[3][lane]));
        int cnt = s1 - s0;
        if (cnt == 0) smax = 0.f;
        f[lane] = ssum / (float)max(cnt, 1);
        f[64 + lane] = smax;
        f[128 + lane] = ssum;
    }
    if (t < 4) f[192 + t] = x[(size_t)s0 * 4 + t];
    __syncthreads();
    float o = b1[t];
    for (int c = 0; c < 196; ++c) o += f[c] * W1[c * 256 + t];
    o = silu_f(o);
    float s = o, s2v = o * o;
#pragma unroll
    for (int m = 1; m < 64; m <<= 1) { s += __shfl_xor(s, m, 64); s2v += __shfl_xor(s2v, m, 64); }
    if (lane == 0) { lred[w] = s; lred[4 + w] = s2v; }
    __syncthreads();
    float tot = lred[0] + lred[1] + lred[2] + lred[3];
    float tot2 = lred[4] + lred[5] + lred[6] + lred[7];
    float mu = tot * (1.f / 256.f);
    float var = tot2 * (1.f / 256.f) - mu * mu;
    float u = (o - mu) * rsqrtf(var + 1e-5f) * lg[t] + lb[t];
    float4 w2r = reinterpret_cast<const float4*>(W2)[t];
    float p0 = u * w2r.x, p1 = u * w2r.y, p2 = u * w2r.z, p3 = u * w2r.w;
#pragma unroll
    for (int m = 1; m < 64; m <<= 1) {
        p0 += __shfl_xor(p0, m, 64); p1 += __shfl_xor(p1, m, 64);
        p2 += __shfl_xor(p2, m, 64); p3 += __shfl_xor(p3, m, 64);
    }
    if (lane == 0) { pr[w][0] = p0; pr[w][1] = p1; pr[w][2] = p2; pr[w][3] = p3; }
    __syncthreads();
    if (t < 4) out[g * 4 + t] = pr[0][t] + pr[1][t] + pr[2][t] + pr[3][t] + b2[t];
}

// ---------------- launch ----------------

extern "C" void kernel_launch(void* const* d_in, const int* in_sizes, int n_in,
                              void* d_out, int out_size, void* d_ws, size_t ws_size,
                              hipStream_t stream)
{
    const float* x    = (const float*)d_in[0];
    const int*   ei   = (const int*)d_in[1];
    const int*   ptr  = (const int*)d_in[3];
    const float* Wl0  = (const float*)d_in[4];
    const float* bl0  = (const float*)d_in[5];
    const float* Wr0  = (const float*)d_in[6];
    const float* Wl   = (const float*)d_in[7];
    const float* bl   = (const float*)d_in[8];
    const float* Wr   = (const float*)d_in[9];
    const float* Wres = (const float*)d_in[10];
    const float* bres = (const float*)d_in[11];
    const float* lng  = (const float*)d_in[12];
    const float* lnb  = (const float*)d_in[13];
    const float* mW1  = (const float*)d_in[14];
    const float* mb1  = (const float*)d_in[15];
    const float* mg   = (const float*)d_in[16];
    const float* mbn  = (const float*)d_in[17];
    const float* mW2  = (const float*)d_in[18];
    const float* mb2  = (const float*)d_in[19];
    const float* rW1  = (const float*)d_in[20];
    const float* rb1  = (const float*)d_in[21];
    const float* rg   = (const float*)d_in[22];
    const float* rbn  = (const float*)d_in[23];
    const float* rW2  = (const float*)d_in[24];
    const float* rb2  = (const float*)d_in[25];
    float* out = (float*)d_out;

    int N = in_sizes[0] / 4;
    int E = in_sizes[1] / 2;
    int NG = in_sizes[3] - 1;
    int nchunk = (N + 255) / 256;
    int neblk  = (E + 255) / 256;
    int nmlp   = (N + 63) / 64;

    char* ws = (char*)d_ws;
    size_t o = 0;
    auto alloc = [&](size_t bytes) -> void* {
        void* p = ws + o;
        o += (bytes + 255) & ~(size_t)255;
        return p;
    };
    int*   off   = (int*)alloc((size_t)(N + 1) * 4);
    int*   cnt   = (int*)alloc((size_t)N * 4);
    int*   cur   = (int*)alloc((size_t)N * 4);
    int*   bsum  = (int*)alloc((size_t)nchunk * 4);
    int*   boff  = (int*)alloc((size_t)nchunk * 4);
    int*   csr   = (int*)alloc((size_t)E * 4);
    float* ha    = (float*)alloc((size_t)N * 64 * 4);
    float* hb    = (float*)alloc((size_t)N * 64 * 4);
    float* aggws = (float*)alloc((size_t)N * 128 * 4);
    float* w1t   = (float*)alloc((size_t)256 * 64 * 4);
    float* g2    = (float*)alloc((size_t)256 * 64 * 4);
    float* k12   = (float*)alloc((size_t)128 * 4);

    // cnt and cur are adjacent in the workspace: one memset covers both
    hipMemsetAsync(cnt, 0, (size_t)((char*)cur - (char*)cnt) + (size_t)N * 4, stream);
    k_prep<<<4, 256, 0, stream>>>(mW1, mg, mbn, mW2, mb2, w1t, g2, k12);
    k_count<<<neblk, 256, 0, stream>>>(ei, cnt, E);
    k_scanA<<<nchunk, 256, 0, stream>>>(cnt, bsum, N);
    k_scanB<<<1, 64, 0, stream>>>(bsum, boff, off, nchunk, N);
    k_scanC<<<nchunk, 256, 0, stream>>>(cnt, boff, off, N);
    k_fill<<<neblk, 256, 0, stream>>>(ei, off, cur, csr, E);

    k_layer0<<<nchunk, 256, 0, stream>>>(x, ha, off, csr, Wl0, bl0, Wr0, Wres, bres, lng, lnb, N);

    k_agg<<<2048, 256, 0, stream>>>(ha, aggws, off, csr, N);
    k_smm<<<1024, 256, 0, stream>>>(aggws, ha, hb, Wl,                bl,       Wr,               lng + 64,  lnb + 64,  N);
    k_agg<<<2048, 256, 0, stream>>>(hb, aggws, off, csr, N);
    k_smm<<<1024, 256, 0, stream>>>(aggws, hb, ha, Wl + 128 * 64,     bl + 64,  Wr + 64 * 64,     lng + 128, lnb + 128, N);
    k_agg<<<2048, 256, 0, stream>>>(ha, aggws, off, csr, N);
    k_smm<<<1024, 256, 0, stream>>>(aggws, ha, hb, Wl + 2 * 128 * 64, bl + 128, Wr + 2 * 64 * 64, lng + 192, lnb + 192, N);

    k_mlp<<<nmlp, 64, 0, stream>>>(hb, ha, w1t, mb1, g2, k12, N);
    k_readout<<<NG, 256, 0, stream>>>(ha, x, ptr, rW1, rb1, rg, rbn, rW2, rb2, out);
}

// Round 6
// 1067.409 us; speedup vs baseline: 1.3194x; 1.3194x over previous
//
#include <hip/hip_runtime.h>
#include <math.h>

#define NEG_INF (-__builtin_inff())

__device__ __forceinline__ float rlane(float x, int l) {
    return __int_as_float(__builtin_amdgcn_readlane(__float_as_int(x), l));
}

__device__ __forceinline__ float silu_f(float y) {
    return y / (1.f + __expf(-y));
}

// ---------------- CSR build ----------------

__global__ void k_count(const int* __restrict__ ei, int* __restrict__ cnt, int E) {
    int e = blockIdx.x * 256 + threadIdx.x;
    if (e < E) atomicAdd(&cnt[ei[E + e]], 1);
}

__global__ void k_scanA(const int* __restrict__ cnt, int* __restrict__ bsum, int N) {
    __shared__ int sh[4];
    int i = blockIdx.x * 256 + threadIdx.x;
    int v = (i < N) ? cnt[i] : 0;
#pragma unroll
    for (int m = 1; m < 64; m <<= 1) v += __shfl_xor(v, m, 64);
    int w = threadIdx.x >> 6;
    if ((threadIdx.x & 63) == 0) sh[w] = v;
    __syncthreads();
    if (threadIdx.x == 0) bsum[blockIdx.x] = sh[0] + sh[1] + sh[2] + sh[3];
}

__global__ void k_scanB(const int* __restrict__ bsum, int* __restrict__ boff,
                        int* __restrict__ off, int nb, int N) {
    int lane = threadIdx.x & 63;
    int run = 0;
    for (int base = 0; base < nb; base += 64) {
        int i = base + lane;
        int ov = (i < nb) ? bsum[i] : 0;
        int v = ov;
#pragma unroll
        for (int s = 1; s < 64; s <<= 1) {
            int q = __shfl_up(v, s, 64);
            if (lane >= s) v += q;
        }
        if (i < nb) boff[i] = run + v - ov;
        run += __shfl(v, 63, 64);
    }
    if (lane == 0) off[N] = run;
}

__global__ void k_scanC(const int* __restrict__ cnt, const int* __restrict__ boff,
                        int* __restrict__ off, int N) {
    __shared__ int ls[256];
    int t = threadIdx.x;
    int i = blockIdx.x * 256 + t;
    int myv = (i < N) ? cnt[i] : 0;
    ls[t] = myv;
    __syncthreads();
#pragma unroll
    for (int s = 1; s < 256; s <<= 1) {
        int add = (t >= s) ? ls[t - s] : 0;
        __syncthreads();
        ls[t] += add;
        __syncthreads();
    }
    if (i < N) off[i] = boff[blockIdx.x] + ls[t] - myv;
}

__global__ void k_fill(const int* __restrict__ ei, const int* __restrict__ off,
                       int* __restrict__ cur, int* __restrict__ csr, int E) {
    int e = blockIdx.x * 256 + threadIdx.x;
    if (e < E) {
        int d = ei[E + e];
        int pos = off[d] + atomicAdd(&cur[d], 1);
        csr[pos] = ei[e];
    }
}

// ---------------- Layer 0 (N_IN=4), one thread per node ----------------

__global__ __launch_bounds__(256, 4)
void k_layer0(const float* __restrict__ x, float* __restrict__ hout,
              const int* __restrict__ off, const int* __restrict__ csr,
              const float* __restrict__ Wl0, const float* __restrict__ bl0,
              const float* __restrict__ Wr0, const float* __restrict__ Wres,
              const float* __restrict__ bres, const float* __restrict__ lg,
              const float* __restrict__ lb, int N)
{
    __shared__ float sWl[512], sWr[256], sWres[256], sC[256];
    int t = threadIdx.x;
    sWl[t] = Wl0[t]; sWl[256 + t] = Wl0[256 + t];
    sWr[t] = Wr0[t];
    sWres[t] = Wres[t];
    if (t < 64) { sC[t] = bl0[t]; sC[64 + t] = bres[t]; sC[128 + t] = lg[t]; sC[192 + t] = lb[t]; }
    __syncthreads();
    int v = blockIdx.x * 256 + t;
    if (v >= N) return;
    const float4* X4 = reinterpret_cast<const float4*>(x);
    float4 xv = X4[v];
    int s0 = off[v], s1 = off[v + 1];
    float4 mx = {NEG_INF, NEG_INF, NEG_INF, NEG_INF};
    float4 sm = {0.f, 0.f, 0.f, 0.f};
    for (int e = s0; e < s1; e += 4) {
        int last = s1 - 1;
        int i0 = csr[e];
        int i1 = csr[min(e + 1, last)];
        int i2 = csr[min(e + 2, last)];
        int i3 = csr[min(e + 3, last)];
        float4 a0 = X4[i0], a1 = X4[i1], a2 = X4[i2], a3 = X4[i3];
        mx.x = fmaxf(fmaxf(fmaxf(mx.x, a0.x), fmaxf(a1.x, a2.x)), a3.x);
        mx.y = fmaxf(fmaxf(fmaxf(mx.y, a0.y), fmaxf(a1.y, a2.y)), a3.y);
        mx.z = fmaxf(fmaxf(fmaxf(mx.z, a0.z), fmaxf(a1.z, a2.z)), a3.z);
        mx.w = fmaxf(fmaxf(fmaxf(mx.w, a0.w), fmaxf(a1.w, a2.w)), a3.w);
        bool o1 = e + 1 < s1, o2 = e + 2 < s1, o3 = e + 3 < s1;
        sm.x += a0.x + (o1 ? a1.x : 0.f) + (o2 ? a2.x : 0.f) + (o3 ? a3.x : 0.f);
        sm.y += a0.y + (o1 ? a1.y : 0.f) + (o2 ? a2.y : 0.f) + (o3 ? a3.y : 0.f);
        sm.z += a0.z + (o1 ? a1.z : 0.f) + (o2 ? a2.z : 0.f) + (o3 ? a3.z : 0.f);
        sm.w += a0.w + (o1 ? a1.w : 0.f) + (o2 ? a2.w : 0.f) + (o3 ? a3.w : 0.f);
    }
    int deg = s1 - s0;
    if (deg == 0) { mx.x = 0.f; mx.y = 0.f; mx.z = 0.f; mx.w = 0.f; }
    float inv = 1.f / (float)max(deg, 1);
    float4 mn = {sm.x * inv, sm.y * inv, sm.z * inv, sm.w * inv};
    float a[64];
    float acc1 = 0.f, acc2 = 0.f;
#pragma unroll
    for (int k = 0; k < 64; ++k) {
        float tv = sC[k]
            + mx.x * sWl[k]       + mx.y * sWl[64 + k]  + mx.z * sWl[128 + k] + mx.w * sWl[192 + k]
            + mn.x * sWl[256 + k] + mn.y * sWl[320 + k] + mn.z * sWl[384 + k] + mn.w * sWl[448 + k]
            + xv.x * sWr[k]       + xv.y * sWr[64 + k]  + xv.z * sWr[128 + k] + xv.w * sWr[192 + k];
        a[k] = tv; acc1 += tv; acc2 += tv * tv;
    }
    float mu = acc1 * (1.f / 64.f);
    float var = acc2 * (1.f / 64.f) - mu * mu;
    float rs = rsqrtf(var + 1e-5f);
    float* orow = hout + (size_t)v * 64;
#pragma unroll
    for (int k = 0; k < 64; ++k) {
        float res = sC[64 + k] + xv.x * sWres[k] + xv.y * sWres[64 + k]
                  + xv.z * sWres[128 + k] + xv.w * sWres[192 + k];
        float y = (a[k] - mu) * rs * sC[128 + k] + sC[192 + k] + res;
        orow[k] = silu_f(y);
    }
}

// ---------------- k_agg: gather + aggregate only (high occupancy) ----------------
// writes aggws[node][0..63]=max, [64..127]=mean

__global__ __launch_bounds__(256, 8)
void k_agg(const float* __restrict__ hin, float* __restrict__ aggws,
           const int* __restrict__ off, const int* __restrict__ csr, int N)
{
    int lane = threadIdx.x & 63;
    int gw = (blockIdx.x * blockDim.x + threadIdx.x) >> 6;
    int nw = (gridDim.x * blockDim.x) >> 6;
    for (int v = gw; v < N; v += nw) {
        int s0 = off[v], s1 = off[v + 1];
        float mx = NEG_INF, sm = 0.f;
        for (int cb = s0; cb < s1; cb += 64) {
            int cdeg = min(64, s1 - cb);
            int idxv = csr[min(cb + lane, s1 - 1)];
            for (int b = 0; b < cdeg; b += 8) {
                float vv[8];
#pragma unroll
                for (int u = 0; u < 8; ++u) {
                    int iu = __builtin_amdgcn_readlane(idxv, b + u);
                    vv[u] = hin[((size_t)iu << 6) + lane];
                }
#pragma unroll
                for (int u = 0; u < 8; ++u) {
                    mx = fmaxf(mx, vv[u]);                // dup rows don't change max
                    sm += (b + u < cdeg) ? vv[u] : 0.f;   // mask dups out of sum
                }
            }
        }
        int deg = s1 - s0;
        if (deg == 0) mx = 0.f;
        float mean = sm / (float)max(deg, 1);
        aggws[((size_t)v << 7) + lane] = mx;
        aggws[((size_t)v << 7) + 64 + lane] = mean;
    }
}

// ---------------- k_smm: matmul+LN+silu, readlane structure + pinned weights ----------------

__global__ __launch_bounds__(256, 2)
void k_smm(const float* __restrict__ aggws, const float* __restrict__ hin,
           float* __restrict__ hout,
           const float* __restrict__ Wl, const float* __restrict__ bl,
           const float* __restrict__ Wr, const float* __restrict__ lg,
           const float* __restrict__ lb, int N)
{
    int lane = threadIdx.x & 63;
    int gw = (blockIdx.x * blockDim.x + threadIdx.x) >> 6;
    int nw = (gridDim.x * blockDim.x) >> 6;
    float wl[128], wr[64];
#pragma unroll
    for (int c = 0; c < 128; ++c) wl[c] = Wl[c * 64 + lane];
#pragma unroll
    for (int c = 0; c < 64; ++c) wr[c] = Wr[c * 64 + lane];
    // pin: round-4 ran VGPR_Count=112 -> compiler re-fetched weights from
    // global per node (VALU 2.3x over instruction floor). Pins force residency.
#pragma unroll
    for (int c = 0; c < 128; ++c) asm volatile("" : "+v"(wl[c]));
#pragma unroll
    for (int c = 0; c < 64; ++c) asm volatile("" : "+v"(wr[c]));
    float blv = bl[lane], gv = lg[lane], bv = lb[lane];
    for (int v = gw; v < N; v += nw) {
        float mx   = aggws[((size_t)v << 7) + lane];
        float mean = aggws[((size_t)v << 7) + 64 + lane];
        float hs   = hin[((size_t)v << 6) + lane];
        float a0 = blv, a1 = 0.f, a2 = 0.f;
#pragma unroll
        for (int c = 0; c < 64; ++c) {
            a0 += rlane(mx, c) * wl[c];
            a1 += rlane(mean, c) * wl[64 + c];
            a2 += rlane(hs, c) * wr[c];
        }
        float acc = a0 + a1 + a2;
        float mu = acc;
#pragma unroll
        for (int m = 1; m < 64; m <<= 1) mu += __shfl_xor(mu, m, 64);
        mu *= (1.f / 64.f);
        float xc = acc - mu;
        float var = xc * xc;
#pragma unroll
        for (int m = 1; m < 64; m <<= 1) var += __shfl_xor(var, m, 64);
        var *= (1.f / 64.f);
        float y = xc * rsqrtf(var + 1e-5f) * gv + bv + hs;
        hout[((size_t)v << 6) + lane] = silu_f(y);
    }
}

// ---------------- MLP: readlane structure + pinned weights, 2-wave/EU budget ----------------

__global__ __launch_bounds__(256, 2)
void k_mlp(const float* __restrict__ hin, float* __restrict__ hout,
           const float* __restrict__ W1, const float* __restrict__ b1,
           const float* __restrict__ lg, const float* __restrict__ lb,
           const float* __restrict__ W2, const float* __restrict__ b2, int N)
{
    __shared__ float red[8];
    __shared__ float part[4][64];
    int lane = threadIdx.x & 63;
    int w = threadIdx.x >> 6;
    int kk = (w << 6) + lane;          // channel in [0,256)
    float w1c[64], w2c[64];
#pragma unroll
    for (int c = 0; c < 64; ++c) w1c[c] = W1[c * 256 + kk];
#pragma unroll
    for (int i = 0; i < 64; ++i) w2c[i] = W2[(((w << 6) + i) << 6) + lane];
    // pin: round-4 ran VGPR_Count=80 with 128 weight floats declared ->
    // reload-from-global per node was the 2.3x VALU overhead. (256,2) gives
    // the 256-reg budget; (256,3)'s ~170 cap is why the compiler spilled.
#pragma unroll
    for (int c = 0; c < 64; ++c) asm volatile("" : "+v"(w1c[c]));
#pragma unroll
    for (int i = 0; i < 64; ++i) asm volatile("" : "+v"(w2c[i]));
    float b1v = b1[kk], gv = lg[kk], bnv = lb[kk];
    for (int v = blockIdx.x; v < N; v += gridDim.x) {
        float hreg = hin[(size_t)v * 64 + lane];
        float tv = b1v;
#pragma unroll
        for (int c = 0; c < 64; ++c) tv += rlane(hreg, c) * w1c[c];
        tv = silu_f(tv);
        float s = tv, s2 = tv * tv;
#pragma unroll
        for (int m = 1; m < 64; m <<= 1) { s += __shfl_xor(s, m, 64); s2 += __shfl_xor(s2, m, 64); }
        if (lane == 0) { red[w] = s; red[4 + w] = s2; }
        __syncthreads();
        float tot = red[0] + red[1] + red[2] + red[3];
        float tot2 = red[4] + red[5] + red[6] + red[7];
        float mu = tot * (1.f / 256.f);
        float var = tot2 * (1.f / 256.f) - mu * mu;
        float u = (tv - mu) * rsqrtf(var + 1e-5f) * gv + bnv;
        float p = 0.f;
#pragma unroll
        for (int i = 0; i < 64; ++i) p += rlane(u, i) * w2c[i];
        part[w][lane] = p;
        __syncthreads();
        if (w == 0) {
            float o = part[0][lane] + part[1][lane] + part[2][lane] + part[3][lane] + b2[lane];
            hout[(size_t)v * 64 + lane] = o;
        }
    }
}

// ---------------- Readout: block per graph ----------------

__global__ __launch_bounds__(256, 2)
void k_readout(const float* __restrict__ h2, const float* __restrict__ x,
               const int* __restrict__ ptr,
               const float* __restrict__ W1, const float* __restrict__ b1,
               const float* __restrict__ lg, const float* __restrict__ lb,
               const float* __restrict__ W2, const float* __restrict__ b2,
               float* __restrict__ out)
{
    __shared__ float f[196];
    __shared__ float sred[4][64];
    __shared__ float mred[4][64];
    __shared__ float lred[8];
    __shared__ float pr[4][4];
    int t = threadIdx.x, lane = t & 63, w = t >> 6;
    int g = blockIdx.x;
    int s0 = ptr[g], s1 = ptr[g + 1];
    float sm = 0.f, mx = NEG_INF;
    for (int r = s0 + w; r < s1; r += 4) {
        float v = h2[(size_t)r * 64 + lane];
        sm += v; mx = fmaxf(mx, v);
    }
    sred[w][lane] = sm; mred[w][lane] = mx;
    __syncthreads();
    if (w == 0) {
        float ssum = sred[0][lane] + sred[1][lane] + sred[2][lane] + sred[3][lane];
        float smax = fmaxf(fmaxf(mred[0][lane], mred[1][lane]),
                           fmaxf(mred[2][lane], mred[3][lane]));
        int cnt = s1 - s0;
        if (cnt == 0) smax = 0.f;
        f[lane] = ssum / (float)max(cnt, 1);
        f[64 + lane] = smax;
        f[128 + lane] = ssum;
    }
    if (t < 4) f[192 + t] = x[(size_t)s0 * 4 + t];
    __syncthreads();
    float o = b1[t];
    for (int c = 0; c < 196; ++c) o += f[c] * W1[c * 256 + t];
    o = silu_f(o);
    float s = o, s2v = o * o;
#pragma unroll
    for (int m = 1; m < 64; m <<= 1) { s += __shfl_xor(s, m, 64); s2v += __shfl_xor(s2v, m, 64); }
    if (lane == 0) { lred[w] = s; lred[4 + w] = s2v; }
    __syncthreads();
    float tot = lred[0] + lred[1] + lred[2] + lred[3];
    float tot2 = lred[4] + lred[5] + lred[6] + lred[7];
    float mu = tot * (1.f / 256.f);
    float var = tot2 * (1.f / 256.f) - mu * mu;
    float u = (o - mu) * rsqrtf(var + 1e-5f) * lg[t] + lb[t];
    float4 w2r = reinterpret_cast<const float4*>(W2)[t];
    float p0 = u * w2r.x, p1 = u * w2r.y, p2 = u * w2r.z, p3 = u * w2r.w;
#pragma unroll
    for (int m = 1; m < 64; m <<= 1) {
        p0 += __shfl_xor(p0, m, 64); p1 += __shfl_xor(p1, m, 64);
        p2 += __shfl_xor(p2, m, 64); p3 += __shfl_xor(p3, m, 64);
    }
    if (lane == 0) { pr[w][0] = p0; pr[w][1] = p1; pr[w][2] = p2; pr[w][3] = p3; }
    __syncthreads();
    if (t < 4) out[g * 4 + t] = pr[0][t] + pr[1][t] + pr[2][t] + pr[3][t] + b2[t];
}

// ---------------- launch ----------------

extern "C" void kernel_launch(void* const* d_in, const int* in_sizes, int n_in,
                              void* d_out, int out_size, void* d_ws, size_t ws_size,
                              hipStream_t stream)
{
    const float* x    = (const float*)d_in[0];
    const int*   ei   = (const int*)d_in[1];
    const int*   ptr  = (const int*)d_in[3];
    const float* Wl0  = (const float*)d_in[4];
    const float* bl0  = (const float*)d_in[5];
    const float* Wr0  = (const float*)d_in[6];
    const float* Wl   = (const float*)d_in[7];
    const float* bl   = (const float*)d_in[8];
    const float* Wr   = (const float*)d_in[9];
    const float* Wres = (const float*)d_in[10];
    const float* bres = (const float*)d_in[11];
    const float* lng  = (const float*)d_in[12];
    const float* lnb  = (const float*)d_in[13];
    const float* mW1  = (const float*)d_in[14];
    const float* mb1  = (const float*)d_in[15];
    const float* mg   = (const float*)d_in[16];
    const float* mbn  = (const float*)d_in[17];
    const float* mW2  = (const float*)d_in[18];
    const float* mb2  = (const float*)d_in[19];
    const float* rW1  = (const float*)d_in[20];
    const float* rb1  = (const float*)d_in[21];
    const float* rg   = (const float*)d_in[22];
    const float* rbn  = (const float*)d_in[23];
    const float* rW2  = (const float*)d_in[24];
    const float* rb2  = (const float*)d_in[25];
    float* out = (float*)d_out;

    int N = in_sizes[0] / 4;
    int E = in_sizes[1] / 2;
    int NG = in_sizes[3] - 1;
    int nchunk = (N + 255) / 256;
    int neblk  = (E + 255) / 256;

    char* ws = (char*)d_ws;
    size_t o = 0;
    auto alloc = [&](size_t bytes) -> void* {
        void* p = ws + o;
        o += (bytes + 255) & ~(size_t)255;
        return p;
    };
    int*   off   = (int*)alloc((size_t)(N + 1) * 4);
    int*   cnt   = (int*)alloc((size_t)N * 4);
    int*   cur   = (int*)alloc((size_t)N * 4);
    int*   bsum  = (int*)alloc((size_t)nchunk * 4);
    int*   boff  = (int*)alloc((size_t)nchunk * 4);
    int*   csr   = (int*)alloc((size_t)E * 4);
    float* ha    = (float*)alloc((size_t)N * 64 * 4);
    float* hb    = (float*)alloc((size_t)N * 64 * 4);
    float* aggws = (float*)alloc((size_t)N * 128 * 4);

    // cnt and cur are adjacent in the workspace: one memset covers both
    hipMemsetAsync(cnt, 0, (size_t)((char*)cur - (char*)cnt) + (size_t)N * 4, stream);
    k_count<<<neblk, 256, 0, stream>>>(ei, cnt, E);
    k_scanA<<<nchunk, 256, 0, stream>>>(cnt, bsum, N);
    k_scanB<<<1, 64, 0, stream>>>(bsum, boff, off, nchunk, N);
    k_scanC<<<nchunk, 256, 0, stream>>>(cnt, boff, off, N);
    k_fill<<<neblk, 256, 0, stream>>>(ei, off, cur, csr, E);

    k_layer0<<<nchunk, 256, 0, stream>>>(x, ha, off, csr, Wl0, bl0, Wr0, Wres, bres, lng, lnb, N);

    k_agg<<<2048, 256, 0, stream>>>(ha, aggws, off, csr, N);
    k_smm<<<1024, 256, 0, stream>>>(aggws, ha, hb, Wl,                bl,       Wr,               lng + 64,  lnb + 64,  N);
    k_agg<<<2048, 256, 0, stream>>>(hb, aggws, off, csr, N);
    k_smm<<<1024, 256, 0, stream>>>(aggws, hb, ha, Wl + 128 * 64,     bl + 64,  Wr + 64 * 64,     lng + 128, lnb + 128, N);
    k_agg<<<2048, 256, 0, stream>>>(ha, aggws, off, csr, N);
    k_smm<<<1024, 256, 0, stream>>>(aggws, ha, hb, Wl + 2 * 128 * 64, bl + 128, Wr + 2 * 64 * 64, lng + 192, lnb + 192, N);

    k_mlp<<<2048, 256, 0, stream>>>(hb, ha, mW1, mb1, mg, mbn, mW2, mb2, N);
    k_readout<<<NG, 256, 0, stream>>>(ha, x, ptr, rW1, rb1, rg, rbn, rW2, rb2, out);
}

// Round 7
// 878.799 us; speedup vs baseline: 1.6026x; 1.2146x over previous
//
#include <hip/hip_runtime.h>
#include <math.h>

#define NEG_INF (-__builtin_inff())

typedef __attribute__((ext_vector_type(8))) short short8;    // 8 bf16 = 4 VGPR
typedef __attribute__((ext_vector_type(4))) float f32x4;

__device__ __forceinline__ float rlane(float x, int l) {
    return __int_as_float(__builtin_amdgcn_readlane(__float_as_int(x), l));
}

__device__ __forceinline__ float silu_f(float y) {
    return y / (1.f + __expf(-y));
}

// bf16 round-to-nearest-even helpers for split-precision
__device__ __forceinline__ unsigned short f2bh(float x) {
    unsigned int u = __float_as_uint(x);
    u += 0x7fffu + ((u >> 16) & 1u);
    return (unsigned short)(u >> 16);
}
__device__ __forceinline__ float bh2f(unsigned short h) {
    return __uint_as_float(((unsigned int)h) << 16);
}

// ---------------- CSR build ----------------

__global__ void k_count(const int* __restrict__ ei, int* __restrict__ cnt, int E) {
    int e = blockIdx.x * 256 + threadIdx.x;
    if (e < E) atomicAdd(&cnt[ei[E + e]], 1);
}

__global__ void k_scanA(const int* __restrict__ cnt, int* __restrict__ bsum, int N) {
    __shared__ int sh[4];
    int i = blockIdx.x * 256 + threadIdx.x;
    int v = (i < N) ? cnt[i] : 0;
#pragma unroll
    for (int m = 1; m < 64; m <<= 1) v += __shfl_xor(v, m, 64);
    int w = threadIdx.x >> 6;
    if ((threadIdx.x & 63) == 0) sh[w] = v;
    __syncthreads();
    if (threadIdx.x == 0) bsum[blockIdx.x] = sh[0] + sh[1] + sh[2] + sh[3];
}

__global__ void k_scanB(const int* __restrict__ bsum, int* __restrict__ boff,
                        int* __restrict__ off, int nb, int N) {
    int lane = threadIdx.x & 63;
    int run = 0;
    for (int base = 0; base < nb; base += 64) {
        int i = base + lane;
        int ov = (i < nb) ? bsum[i] : 0;
        int v = ov;
#pragma unroll
        for (int s = 1; s < 64; s <<= 1) {
            int q = __shfl_up(v, s, 64);
            if (lane >= s) v += q;
        }
        if (i < nb) boff[i] = run + v - ov;
        run += __shfl(v, 63, 64);
    }
    if (lane == 0) off[N] = run;
}

__global__ void k_scanC(const int* __restrict__ cnt, const int* __restrict__ boff,
                        int* __restrict__ off, int N) {
    __shared__ int ls[256];
    int t = threadIdx.x;
    int i = blockIdx.x * 256 + t;
    int myv = (i < N) ? cnt[i] : 0;
    ls[t] = myv;
    __syncthreads();
#pragma unroll
    for (int s = 1; s < 256; s <<= 1) {
        int add = (t >= s) ? ls[t - s] : 0;
        __syncthreads();
        ls[t] += add;
        __syncthreads();
    }
    if (i < N) off[i] = boff[blockIdx.x] + ls[t] - myv;
}

__global__ void k_fill(const int* __restrict__ ei, const int* __restrict__ off,
                       int* __restrict__ cur, int* __restrict__ csr, int E) {
    int e = blockIdx.x * 256 + threadIdx.x;
    if (e < E) {
        int d = ei[E + e];
        int pos = off[d] + atomicAdd(&cur[d], 1);
        csr[pos] = ei[e];
    }
}

// ---------------- Prep: MFMA-fragment-packed MLP weights (bf16 hi/lo) ----------------
// w1f[(nt*2+kc)*64+lane][i] = W1[c][j], c=kc*32+(lane>>4)*8+i, j=nt*16+(lane&15)  (nt<16)
// w2f[(nt2*8+kc2)*64+lane][i] = g[j]*W2[j][o], j=kc2*32+(lane>>4)*8+i, o=nt2*16+(lane&15)
// k12[o] = sum_j bn_j*W2[j][o] + b2[o];  k12[64+o] = sum_j g_j*W2[j][o]

__global__ void k_prep(const float* __restrict__ mW1, const float* __restrict__ mg,
                       const float* __restrict__ mbn, const float* __restrict__ mW2,
                       const float* __restrict__ mb2,
                       unsigned short* __restrict__ w1fh, unsigned short* __restrict__ w1fl,
                       unsigned short* __restrict__ w2fh, unsigned short* __restrict__ w2fl,
                       float* __restrict__ k12)
{
    int b = blockIdx.x, t = threadIdx.x;
    if (b == 0) {
        for (int idx = t; idx < 2048; idx += 256) {
            int nt = idx >> 7, rem = idx & 127;
            int kc = rem >> 6, ln = rem & 63;
#pragma unroll
            for (int i = 0; i < 8; ++i) {
                int c = kc * 32 + (ln >> 4) * 8 + i;
                int j = nt * 16 + (ln & 15);
                float v = mW1[c * 256 + j];
                unsigned short hi = f2bh(v);
                unsigned short lo = f2bh(v - bh2f(hi));
                w1fh[idx * 8 + i] = hi;
                w1fl[idx * 8 + i] = lo;
            }
        }
    } else if (b == 1) {
        for (int idx = t; idx < 2048; idx += 256) {
            int nt2 = idx >> 9, rem = idx & 511;
            int kc2 = rem >> 6, ln = rem & 63;
#pragma unroll
            for (int i = 0; i < 8; ++i) {
                int j = kc2 * 32 + (ln >> 4) * 8 + i;
                int o = nt2 * 16 + (ln & 15);
                float v = mg[j] * mW2[j * 64 + o];
                unsigned short hi = f2bh(v);
                unsigned short lo = f2bh(v - bh2f(hi));
                w2fh[idx * 8 + i] = hi;
                w2fl[idx * 8 + i] = lo;
            }
        }
    } else if (b == 2 && t < 64) {
        float a1 = 0.f, a2 = 0.f;
        for (int j = 0; j < 256; ++j) {
            a1 += mbn[j] * mW2[j * 64 + t];
            a2 += mg[j]  * mW2[j * 64 + t];
        }
        k12[t] = a1 + mb2[t];
        k12[64 + t] = a2;
    }
}

// ---------------- Layer 0 (N_IN=4), one thread per node ----------------

__global__ __launch_bounds__(256, 4)
void k_layer0(const float* __restrict__ x, float* __restrict__ hout,
              const int* __restrict__ off, const int* __restrict__ csr,
              const float* __restrict__ Wl0, const float* __restrict__ bl0,
              const float* __restrict__ Wr0, const float* __restrict__ Wres,
              const float* __restrict__ bres, const float* __restrict__ lg,
              const float* __restrict__ lb, int N)
{
    __shared__ float sWl[512], sWr[256], sWres[256], sC[256];
    int t = threadIdx.x;
    sWl[t] = Wl0[t]; sWl[256 + t] = Wl0[256 + t];
    sWr[t] = Wr0[t];
    sWres[t] = Wres[t];
    if (t < 64) { sC[t] = bl0[t]; sC[64 + t] = bres[t]; sC[128 + t] = lg[t]; sC[192 + t] = lb[t]; }
    __syncthreads();
    int v = blockIdx.x * 256 + t;
    if (v >= N) return;
    const float4* X4 = reinterpret_cast<const float4*>(x);
    float4 xv = X4[v];
    int s0 = off[v], s1 = off[v + 1];
    float4 mx = {NEG_INF, NEG_INF, NEG_INF, NEG_INF};
    float4 sm = {0.f, 0.f, 0.f, 0.f};
    for (int e = s0; e < s1; e += 4) {
        int last = s1 - 1;
        int i0 = csr[e];
        int i1 = csr[min(e + 1, last)];
        int i2 = csr[min(e + 2, last)];
        int i3 = csr[min(e + 3, last)];
        float4 a0 = X4[i0], a1 = X4[i1], a2 = X4[i2], a3 = X4[i3];
        mx.x = fmaxf(fmaxf(fmaxf(mx.x, a0.x), fmaxf(a1.x, a2.x)), a3.x);
        mx.y = fmaxf(fmaxf(fmaxf(mx.y, a0.y), fmaxf(a1.y, a2.y)), a3.y);
        mx.z = fmaxf(fmaxf(fmaxf(mx.z, a0.z), fmaxf(a1.z, a2.z)), a3.z);
        mx.w = fmaxf(fmaxf(fmaxf(mx.w, a0.w), fmaxf(a1.w, a2.w)), a3.w);
        bool o1 = e + 1 < s1, o2 = e + 2 < s1, o3 = e + 3 < s1;
        sm.x += a0.x + (o1 ? a1.x : 0.f) + (o2 ? a2.x : 0.f) + (o3 ? a3.x : 0.f);
        sm.y += a0.y + (o1 ? a1.y : 0.f) + (o2 ? a2.y : 0.f) + (o3 ? a3.y : 0.f);
        sm.z += a0.z + (o1 ? a1.z : 0.f) + (o2 ? a2.z : 0.f) + (o3 ? a3.z : 0.f);
        sm.w += a0.w + (o1 ? a1.w : 0.f) + (o2 ? a2.w : 0.f) + (o3 ? a3.w : 0.f);
    }
    int deg = s1 - s0;
    if (deg == 0) { mx.x = 0.f; mx.y = 0.f; mx.z = 0.f; mx.w = 0.f; }
    float inv = 1.f / (float)max(deg, 1);
    float4 mn = {sm.x * inv, sm.y * inv, sm.z * inv, sm.w * inv};
    float a[64];
    float acc1 = 0.f, acc2 = 0.f;
#pragma unroll
    for (int k = 0; k < 64; ++k) {
        float tv = sC[k]
            + mx.x * sWl[k]       + mx.y * sWl[64 + k]  + mx.z * sWl[128 + k] + mx.w * sWl[192 + k]
            + mn.x * sWl[256 + k] + mn.y * sWl[320 + k] + mn.z * sWl[384 + k] + mn.w * sWl[448 + k]
            + xv.x * sWr[k]       + xv.y * sWr[64 + k]  + xv.z * sWr[128 + k] + xv.w * sWr[192 + k];
        a[k] = tv; acc1 += tv; acc2 += tv * tv;
    }
    float mu = acc1 * (1.f / 64.f);
    float var = acc2 * (1.f / 64.f) - mu * mu;
    float rs = rsqrtf(var + 1e-5f);
    float* orow = hout + (size_t)v * 64;
#pragma unroll
    for (int k = 0; k < 64; ++k) {
        float res = sC[64 + k] + xv.x * sWres[k] + xv.y * sWres[64 + k]
                  + xv.z * sWres[128 + k] + xv.w * sWres[192 + k];
        float y = (a[k] - mu) * rs * sC[128 + k] + sC[192 + k] + res;
        orow[k] = silu_f(y);
    }
}

// ---------------- k_agg: gather + aggregate only (high occupancy) ----------------

__global__ __launch_bounds__(256, 8)
void k_agg(const float* __restrict__ hin, float* __restrict__ aggws,
           const int* __restrict__ off, const int* __restrict__ csr, int N)
{
    int lane = threadIdx.x & 63;
    int gw = (blockIdx.x * blockDim.x + threadIdx.x) >> 6;
    int nw = (gridDim.x * blockDim.x) >> 6;
    for (int v = gw; v < N; v += nw) {
        int s0 = off[v], s1 = off[v + 1];
        float mx = NEG_INF, sm = 0.f;
        for (int cb = s0; cb < s1; cb += 64) {
            int cdeg = min(64, s1 - cb);
            int idxv = csr[min(cb + lane, s1 - 1)];
            for (int b = 0; b < cdeg; b += 8) {
                float vv[8];
#pragma unroll
                for (int u = 0; u < 8; ++u) {
                    int iu = __builtin_amdgcn_readlane(idxv, b + u);
                    vv[u] = hin[((size_t)iu << 6) + lane];
                }
#pragma unroll
                for (int u = 0; u < 8; ++u) {
                    mx = fmaxf(mx, vv[u]);                // dup rows don't change max
                    sm += (b + u < cdeg) ? vv[u] : 0.f;   // mask dups out of sum
                }
            }
        }
        int deg = s1 - s0;
        if (deg == 0) mx = 0.f;
        float mean = sm / (float)max(deg, 1);
        aggws[((size_t)v << 7) + lane] = mx;
        aggws[((size_t)v << 7) + 64 + lane] = mean;
    }
}

// ---------------- k_smm: matmul+LN+silu, round-4 readlane structure ----------------

__global__ __launch_bounds__(256, 2)
void k_smm(const float* __restrict__ aggws, const float* __restrict__ hin,
           float* __restrict__ hout,
           const float* __restrict__ Wl, const float* __restrict__ bl,
           const float* __restrict__ Wr, const float* __restrict__ lg,
           const float* __restrict__ lb, int N)
{
    int lane = threadIdx.x & 63;
    int gw = (blockIdx.x * blockDim.x + threadIdx.x) >> 6;
    int nw = (gridDim.x * blockDim.x) >> 6;
    float wl[128], wr[64];
#pragma unroll
    for (int c = 0; c < 128; ++c) wl[c] = Wl[c * 64 + lane];
#pragma unroll
    for (int c = 0; c < 64; ++c) wr[c] = Wr[c * 64 + lane];
    float blv = bl[lane], gv = lg[lane], bv = lb[lane];
    for (int v = gw; v < N; v += nw) {
        float mx   = aggws[((size_t)v << 7) + lane];
        float mean = aggws[((size_t)v << 7) + 64 + lane];
        float hs   = hin[((size_t)v << 6) + lane];
        float a0 = blv, a1 = 0.f, a2 = 0.f;
#pragma unroll
        for (int c = 0; c < 64; ++c) {
            a0 += rlane(mx, c) * wl[c];
            a1 += rlane(mean, c) * wl[64 + c];
            a2 += rlane(hs, c) * wr[c];
        }
        float acc = a0 + a1 + a2;
        float mu = acc;
#pragma unroll
        for (int m = 1; m < 64; m <<= 1) mu += __shfl_xor(mu, m, 64);
        mu *= (1.f / 64.f);
        float xc = acc - mu;
        float var = xc * xc;
#pragma unroll
        for (int m = 1; m < 64; m <<= 1) var += __shfl_xor(var, m, 64);
        var *= (1.f / 64.f);
        float y = xc * rsqrtf(var + 1e-5f) * gv + bv + hs;
        hout[((size_t)v << 6) + lane] = silu_f(y);
    }
}

// ---------------- k_mlpm: MFMA MLP, M-tile=64 per block, split-bf16 (3 products) ----------------
// GEMM1: t = h[64x64] @ W1[64x256]; s = silu(t+b1); LN stats over 256
// GEMM2: A_o = s @ (g*W2);  out = rs*A + K1 - rs*mu*K2
// Layouts (HW-verified, learn_hip m89/m92/m120):
//   A: m=lane&15, k=quad*8+i  |  B: n=lane&15, k=quad*8+i  |  C/D: col(n)=lane&15, row(m)=quad*4+reg

__global__ __launch_bounds__(256, 2)
void k_mlpm(const float* __restrict__ hin, float* __restrict__ hout,
            const unsigned short* __restrict__ w1fh, const unsigned short* __restrict__ w1fl,
            const unsigned short* __restrict__ w2fh, const unsigned short* __restrict__ w2fl,
            const float* __restrict__ b1, const float* __restrict__ K12, int N)
{
    __shared__ __align__(16) char lds[70656];
    float* p1 = (float*)lds;                         // [4 waves][64 nodes]
    float* p2 = (float*)(lds + 1024);
    unsigned short* hhi = (unsigned short*)(lds + 2048);   // [64][72] bf16 (phase 1)
    unsigned short* hlo = (unsigned short*)(lds + 11264);
    unsigned int* spack = (unsigned int*)(lds + 2048);     // [64][268] hi<<16|lo (phase 2)

    int t = threadIdx.x;
    int lane = t & 63, w = t >> 6, quad = lane >> 4, l15 = lane & 15;

    // ---- stage h tile -> bf16 hi/lo in LDS ----
    {
        int row = t >> 2, cq = (t & 3) * 16;
        int node0 = blockIdx.x * 64 + row;
        const float4* hr = (const float4*)(hin + (size_t)min(node0, N - 1) * 64 + cq);
        float v[16];
#pragma unroll
        for (int k = 0; k < 4; ++k) {
            float4 f = hr[k];
            v[4 * k] = f.x; v[4 * k + 1] = f.y; v[4 * k + 2] = f.z; v[4 * k + 3] = f.w;
        }
#pragma unroll
        for (int g = 0; g < 2; ++g) {
            short8 ph, pl;
#pragma unroll
            for (int i = 0; i < 8; ++i) {
                float x = v[g * 8 + i];
                unsigned short hi = f2bh(x);
                ph[i] = (short)hi;
                pl[i] = (short)f2bh(x - bh2f(hi));
            }
            int idx = row * 72 + cq + g * 8;
            *(short8*)(hhi + idx) = ph;
            *(short8*)(hlo + idx) = pl;
        }
    }
    __syncthreads();

    // ---- GEMM1: wave w covers j in [w*64, w*64+64) ----
    f32x4 acc[4][4];
#pragma unroll
    for (int mt = 0; mt < 4; ++mt)
#pragma unroll
        for (int nt = 0; nt < 4; ++nt)
            acc[mt][nt] = (f32x4){0.f, 0.f, 0.f, 0.f};
#pragma unroll
    for (int kc = 0; kc < 2; ++kc) {
        short8 ah[4], al[4];
#pragma unroll
        for (int mt = 0; mt < 4; ++mt) {
            int idx = (mt * 16 + l15) * 72 + kc * 32 + quad * 8;
            ah[mt] = *(const short8*)(hhi + idx);
            al[mt] = *(const short8*)(hlo + idx);
        }
#pragma unroll
        for (int nt = 0; nt < 4; ++nt) {
            int fo = (((w * 4 + nt) * 2 + kc) * 64 + lane) * 8;
            short8 bh_ = *(const short8*)(w1fh + fo);
            short8 bl_ = *(const short8*)(w1fl + fo);
#pragma unroll
            for (int mt = 0; mt < 4; ++mt) {
                acc[mt][nt] = __builtin_amdgcn_mfma_f32_16x16x32_bf16(ah[mt], bh_, acc[mt][nt], 0, 0, 0);
                acc[mt][nt] = __builtin_amdgcn_mfma_f32_16x16x32_bf16(al[mt], bh_, acc[mt][nt], 0, 0, 0);
                acc[mt][nt] = __builtin_amdgcn_mfma_f32_16x16x32_bf16(ah[mt], bl_, acc[mt][nt], 0, 0, 0);
            }
        }
    }

    // ---- bias + silu + LN partial stats (per node = mt*16+quad*4+r) ----
    float b1v[4];
#pragma unroll
    for (int nt = 0; nt < 4; ++nt) b1v[nt] = b1[(w * 4 + nt) * 16 + l15];
    float psum[4][4], psq[4][4];
#pragma unroll
    for (int mt = 0; mt < 4; ++mt)
#pragma unroll
        for (int r = 0; r < 4; ++r) { psum[mt][r] = 0.f; psq[mt][r] = 0.f; }
#pragma unroll
    for (int mt = 0; mt < 4; ++mt)
#pragma unroll
        for (int nt = 0; nt < 4; ++nt)
#pragma unroll
            for (int r = 0; r < 4; ++r) {
                float sv = silu_f(acc[mt][nt][r] + b1v[nt]);
                acc[mt][nt][r] = sv;
                psum[mt][r] += sv;
                psq[mt][r] += sv * sv;
            }
#pragma unroll
    for (int mt = 0; mt < 4; ++mt)
#pragma unroll
        for (int r = 0; r < 4; ++r) {
            float a = psum[mt][r], b = psq[mt][r];
#pragma unroll
            for (int m = 1; m < 16; m <<= 1) {
                a += __shfl_xor(a, m, 64);
                b += __shfl_xor(b, m, 64);
            }
            psum[mt][r] = a; psq[mt][r] = b;
        }
    if (l15 == 0) {
#pragma unroll
        for (int mt = 0; mt < 4; ++mt)
#pragma unroll
            for (int r = 0; r < 4; ++r) {
                int nl = mt * 16 + quad * 4 + r;
                p1[w * 64 + nl] = psum[mt][r];
                p2[w * 64 + nl] = psq[mt][r];
            }
    }
    __syncthreads();   // all GEMM1 LDS reads done; partials visible

    // ---- repack s (C layout) -> LDS A-layout rows, bf16 hi|lo packed ----
#pragma unroll
    for (int mt = 0; mt < 4; ++mt)
#pragma unroll
        for (int nt = 0; nt < 4; ++nt)
#pragma unroll
            for (int r = 0; r < 4; ++r) {
                float sv = acc[mt][nt][r];
                unsigned short hi = f2bh(sv);
                unsigned short lo = f2bh(sv - bh2f(hi));
                spack[(mt * 16 + quad * 4 + r) * 268 + (w * 4 + nt) * 16 + l15] =
                    (((unsigned int)hi) << 16) | (unsigned int)lo;
            }
    __syncthreads();

    // ---- GEMM2: wave w handles M-tile mt=w (nodes w*16..w*16+15), full K=256 ----
    f32x4 acc2[4];
#pragma unroll
    for (int nt2 = 0; nt2 < 4; ++nt2) acc2[nt2] = (f32x4){0.f, 0.f, 0.f, 0.f};
#pragma unroll
    for (int kc2 = 0; kc2 < 8; ++kc2) {
        int base = (w * 16 + l15) * 268 + kc2 * 32 + quad * 8;
        uint4 q0 = *(const uint4*)(spack + base);
        uint4 q1 = *(const uint4*)(spack + base + 4);
        unsigned int vv[8] = {q0.x, q0.y, q0.z, q0.w, q1.x, q1.y, q1.z, q1.w};
        short8 ah, al;
#pragma unroll
        for (int i = 0; i < 8; ++i) {
            ah[i] = (short)(vv[i] >> 16);
            al[i] = (short)(vv[i] & 0xffffu);
        }
#pragma unroll
        for (int nt2 = 0; nt2 < 4; ++nt2) {
            int fo = ((nt2 * 8 + kc2) * 64 + lane) * 8;
            short8 bh_ = *(const short8*)(w2fh + fo);
            short8 bl_ = *(const short8*)(w2fl + fo);
            acc2[nt2] = __builtin_amdgcn_mfma_f32_16x16x32_bf16(ah, bh_, acc2[nt2], 0, 0, 0);
            acc2[nt2] = __builtin_amdgcn_mfma_f32_16x16x32_bf16(al, bh_, acc2[nt2], 0, 0, 0);
            acc2[nt2] = __builtin_amdgcn_mfma_f32_16x16x32_bf16(ah, bl_, acc2[nt2], 0, 0, 0);
        }
    }

    // ---- epilogue: LN fold (round-3-verified K12 identity) + store ----
    float k1v[4], k2v[4];
#pragma unroll
    for (int nt2 = 0; nt2 < 4; ++nt2) {
        k1v[nt2] = K12[nt2 * 16 + l15];
        k2v[nt2] = K12[64 + nt2 * 16 + l15];
    }
#pragma unroll
    for (int r = 0; r < 4; ++r) {
        int nl = w * 16 + quad * 4 + r;
        float s1 = p1[nl] + p1[64 + nl] + p1[128 + nl] + p1[192 + nl];
        float s2 = p2[nl] + p2[64 + nl] + p2[128 + nl] + p2[192 + nl];
        float mu = s1 * (1.f / 256.f);
        float var = s2 * (1.f / 256.f) - mu * mu;
        float rs = rsqrtf(var + 1e-5f);
        float rm = rs * mu;
        int node = blockIdx.x * 64 + nl;
        if (node < N) {
#pragma unroll
            for (int nt2 = 0; nt2 < 4; ++nt2)
                hout[(size_t)node * 64 + nt2 * 16 + l15] =
                    rs * acc2[nt2][r] + k1v[nt2] - rm * k2v[nt2];
        }
    }
}

// ---------------- Readout: block per graph ----------------

__global__ __launch_bounds__(256, 2)
void k_readout(const float* __restrict__ h2, const float* __restrict__ x,
               const int* __restrict__ ptr,
               const float* __restrict__ W1, const float* __restrict__ b1,
               const float* __restrict__ lg, const float* __restrict__ lb,
               const float* __restrict__ W2, const float* __restrict__ b2,
               float* __restrict__ out)
{
    __shared__ float f[196];
    __shared__ float sred[4][64];
    __shared__ float mred[4][64];
    __shared__ float lred[8];
    __shared__ float pr[4][4];
    int t = threadIdx.x, lane = t & 63, w = t >> 6;
    int g = blockIdx.x;
    int s0 = ptr[g], s1 = ptr[g + 1];
    float sm = 0.f, mx = NEG_INF;
    for (int r = s0 + w; r < s1; r += 4) {
        float v = h2[(size_t)r * 64 + lane];
        sm += v; mx = fmaxf(mx, v);
    }
    sred[w][lane] = sm; mred[w][lane] = mx;
    __syncthreads();
    if (w == 0) {
        float ssum = sred[0][lane] + sred[1][lane] + sred[2][lane] + sred[3][lane];
        float smax = fmaxf(fmaxf(mred[0][lane], mred[1][lane]),
                           fmaxf(mred[2][lane], mred[3][lane]));
        int cnt = s1 - s0;
        if (cnt == 0) smax = 0.f;
        f[lane] = ssum / (float)max(cnt, 1);
        f[64 + lane] = smax;
        f[128 + lane] = ssum;
    }
    if (t < 4) f[192 + t] = x[(size_t)s0 * 4 + t];
    __syncthreads();
    float o = b1[t];
    for (int c = 0; c < 196; ++c) o += f[c] * W1[c * 256 + t];
    o = silu_f(o);
    float s = o, s2v = o * o;
#pragma unroll
    for (int m = 1; m < 64; m <<= 1) { s += __shfl_xor(s, m, 64); s2v += __shfl_xor(s2v, m, 64); }
    if (lane == 0) { lred[w] = s; lred[4 + w] = s2v; }
    __syncthreads();
    float tot = lred[0] + lred[1] + lred[2] + lred[3];
    float tot2 = lred[4] + lred[5] + lred[6] + lred[7];
    float mu = tot * (1.f / 256.f);
    float var = tot2 * (1.f / 256.f) - mu * mu;
    float u = (o - mu) * rsqrtf(var + 1e-5f) * lg[t] + lb[t];
    float4 w2r = reinterpret_cast<const float4*>(W2)[t];
    float p0 = u * w2r.x, p1 = u * w2r.y, p2 = u * w2r.z, p3 = u * w2r.w;
#pragma unroll
    for (int m = 1; m < 64; m <<= 1) {
        p0 += __shfl_xor(p0, m, 64); p1 += __shfl_xor(p1, m, 64);
        p2 += __shfl_xor(p2, m, 64); p3 += __shfl_xor(p3, m, 64);
    }
    if (lane == 0) { pr[w][0] = p0; pr[w][1] = p1; pr[w][2] = p2; pr[w][3] = p3; }
    __syncthreads();
    if (t < 4) out[g * 4 + t] = pr[0][t] + pr[1][t] + pr[2][t] + pr[3][t] + b2[t];
}

// ---------------- launch ----------------

extern "C" void kernel_launch(void* const* d_in, const int* in_sizes, int n_in,
                              void* d_out, int out_size, void* d_ws, size_t ws_size,
                              hipStream_t stream)
{
    const float* x    = (const float*)d_in[0];
    const int*   ei   = (const int*)d_in[1];
    const int*   ptr  = (const int*)d_in[3];
    const float* Wl0  = (const float*)d_in[4];
    const float* bl0  = (const float*)d_in[5];
    const float* Wr0  = (const float*)d_in[6];
    const float* Wl   = (const float*)d_in[7];
    const float* bl   = (const float*)d_in[8];
    const float* Wr   = (const float*)d_in[9];
    const float* Wres = (const float*)d_in[10];
    const float* bres = (const float*)d_in[11];
    const float* lng  = (const float*)d_in[12];
    const float* lnb  = (const float*)d_in[13];
    const float* mW1  = (const float*)d_in[14];
    const float* mb1  = (const float*)d_in[15];
    const float* mg   = (const float*)d_in[16];
    const float* mbn  = (const float*)d_in[17];
    const float* mW2  = (const float*)d_in[18];
    const float* mb2  = (const float*)d_in[19];
    const float* rW1  = (const float*)d_in[20];
    const float* rb1  = (const float*)d_in[21];
    const float* rg   = (const float*)d_in[22];
    const float* rbn  = (const float*)d_in[23];
    const float* rW2  = (const float*)d_in[24];
    const float* rb2  = (const float*)d_in[25];
    float* out = (float*)d_out;

    int N = in_sizes[0] / 4;
    int E = in_sizes[1] / 2;
    int NG = in_sizes[3] - 1;
    int nchunk = (N + 255) / 256;
    int neblk  = (E + 255) / 256;
    int nblkm  = (N + 63) / 64;

    char* ws = (char*)d_ws;
    size_t o = 0;
    auto alloc = [&](size_t bytes) -> void* {
        void* p = ws + o;
        o += (bytes + 255) & ~(size_t)255;
        return p;
    };
    int*   off   = (int*)alloc((size_t)(N + 1) * 4);
    int*   cnt   = (int*)alloc((size_t)N * 4);
    int*   cur   = (int*)alloc((size_t)N * 4);
    int*   bsum  = (int*)alloc((size_t)nchunk * 4);
    int*   boff  = (int*)alloc((size_t)nchunk * 4);
    int*   csr   = (int*)alloc((size_t)E * 4);
    float* ha    = (float*)alloc((size_t)N * 64 * 4);
    float* hb    = (float*)alloc((size_t)N * 64 * 4);
    float* aggws = (float*)alloc((size_t)N * 128 * 4);
    unsigned short* w1fh = (unsigned short*)alloc(16384 * 2);
    unsigned short* w1fl = (unsigned short*)alloc(16384 * 2);
    unsigned short* w2fh = (unsigned short*)alloc(16384 * 2);
    unsigned short* w2fl = (unsigned short*)alloc(16384 * 2);
    float* k12   = (float*)alloc(128 * 4);

    // cnt and cur are adjacent in the workspace: one memset covers both
    hipMemsetAsync(cnt, 0, (size_t)((char*)cur - (char*)cnt) + (size_t)N * 4, stream);
    k_prep<<<3, 256, 0, stream>>>(mW1, mg, mbn, mW2, mb2, w1fh, w1fl, w2fh, w2fl, k12);
    k_count<<<neblk, 256, 0, stream>>>(ei, cnt, E);
    k_scanA<<<nchunk, 256, 0, stream>>>(cnt, bsum, N);
    k_scanB<<<1, 64, 0, stream>>>(bsum, boff, off, nchunk, N);
    k_scanC<<<nchunk, 256, 0, stream>>>(cnt, boff, off, N);
    k_fill<<<neblk, 256, 0, stream>>>(ei, off, cur, csr, E);

    k_layer0<<<nchunk, 256, 0, stream>>>(x, ha, off, csr, Wl0, bl0, Wr0, Wres, bres, lng, lnb, N);

    k_agg<<<2048, 256, 0, stream>>>(ha, aggws, off, csr, N);
    k_smm<<<1024, 256, 0, stream>>>(aggws, ha, hb, Wl,                bl,       Wr,               lng + 64,  lnb + 64,  N);
    k_agg<<<2048, 256, 0, stream>>>(hb, aggws, off, csr, N);
    k_smm<<<1024, 256, 0, stream>>>(aggws, hb, ha, Wl + 128 * 64,     bl + 64,  Wr + 64 * 64,     lng + 128, lnb + 128, N);
    k_agg<<<2048, 256, 0, stream>>>(ha, aggws, off, csr, N);
    k_smm<<<1024, 256, 0, stream>>>(aggws, ha, hb, Wl + 2 * 128 * 64, bl + 128, Wr + 2 * 64 * 64, lng + 192, lnb + 192, N);

    k_mlpm<<<nblkm, 256, 0, stream>>>(hb, ha, w1fh, w1fl, w2fh, w2fl, mb1, k12, N);
    k_readout<<<NG, 256, 0, stream>>>(ha, x, ptr, rW1, rb1, rg, rbn, rW2, rb2, out);
}

// Round 8
// 753.620 us; speedup vs baseline: 1.8688x; 1.1661x over previous
//
#include <hip/hip_runtime.h>
#include <math.h>

#define NEG_INF (-__builtin_inff())
#define BSHIFT 8                    // 256-node buckets
#define BCAP 6144                   // k_bcsr LDS pair capacity (avg 4096, +5 sigma ~4400)

typedef __attribute__((ext_vector_type(8))) short short8;    // 8 bf16 = 4 VGPR
typedef __attribute__((ext_vector_type(4))) float f32x4;

__device__ __forceinline__ float rlane(float x, int l) {
    return __int_as_float(__builtin_amdgcn_readlane(__float_as_int(x), l));
}

__device__ __forceinline__ float silu_f(float y) {
    return y / (1.f + __expf(-y));
}

// bf16 round-to-nearest-even helpers for split-precision
__device__ __forceinline__ unsigned short f2bh(float x) {
    unsigned int u = __float_as_uint(x);
    u += 0x7fffu + ((u >> 16) & 1u);
    return (unsigned short)(u >> 16);
}
__device__ __forceinline__ float bh2f(unsigned short h) {
    return __uint_as_float(((unsigned int)h) << 16);
}

// ---------------- Bucketed CSR build ----------------
// csr is dst-major, so bucket b's edges occupy the contiguous csr range
// [bbase[b], bbase[b+1]). Writes stay window-local => no line amplification
// (round-7 k_fill: 107 MB WRITE_SIZE for 6.4 MB payload).

// per-block LDS histogram of dst buckets
__global__ __launch_bounds__(256)
void k_bhist(const int* __restrict__ ei, int* __restrict__ btot, int E, int NB) {
    __shared__ int lh[512];
    int t = threadIdx.x;
    lh[t] = 0; lh[t + 256] = 0;
    __syncthreads();
    int base = blockIdx.x * 8192;
    for (int i = t; i < 8192; i += 256) {
        int e = base + i;
        if (e < E) atomicAdd(&lh[ei[E + e] >> BSHIFT], 1);
    }
    __syncthreads();
    if (lh[t]) atomicAdd(&btot[t], lh[t]);
    if (t + 256 < NB && lh[t + 256]) atomicAdd(&btot[t + 256], lh[t + 256]);
}

// one block: exclusive scan of NB (<512) bucket totals -> bbase; bcur = bbase
__global__ __launch_bounds__(256)
void k_bscan(const int* __restrict__ btot, int* __restrict__ bbase,
             int* __restrict__ bcur, int NB, int E) {
    __shared__ int s[512];
    int t = threadIdx.x;
    int v0 = (t < NB) ? btot[t] : 0;
    int v1 = (t + 256 < NB) ? btot[t + 256] : 0;
    s[t] = v0; s[t + 256] = v1;
    __syncthreads();
    for (int st = 1; st < 512; st <<= 1) {
        int a0 = (t >= st) ? s[t - st] : 0;
        int a1 = (t + 256 >= st) ? s[t + 256 - st] : 0;
        __syncthreads();
        s[t] += a0; s[t + 256] += a1;
        __syncthreads();
    }
    if (t < NB)       { bbase[t] = s[t] - v0;             bcur[t] = s[t] - v0; }
    if (t + 256 < NB) { bbase[t + 256] = s[t + 256] - v1; bcur[t + 256] = s[t + 256] - v1; }
    if (t == 0) bbase[NB] = E;
}

// LDS-staged bucket scatter: pairs land bucket-grouped in contiguous runs
__global__ __launch_bounds__(256)
void k_bscatter(const int* __restrict__ ei, int* __restrict__ bcur,
                int2* __restrict__ pairs, int E, int NB) {
    __shared__ int2 sp[8192];                 // 64 KB staging
    __shared__ int lh[512], lsc[512], lcur[512], gb[512];
    int t = threadIdx.x;
    lh[t] = 0; lh[t + 256] = 0; lcur[t] = 0; lcur[t + 256] = 0;
    __syncthreads();
    int base = blockIdx.x * 8192;
    // pass 1: histogram
    for (int i = t; i < 8192; i += 256) {
        int e = base + i;
        if (e < E) atomicAdd(&lh[ei[E + e] >> BSHIFT], 1);
    }
    __syncthreads();
    // inclusive scan of lh into lsc (512-wide, 2 elems/thread)
    lsc[t] = lh[t]; lsc[t + 256] = lh[t + 256];
    __syncthreads();
    for (int st = 1; st < 512; st <<= 1) {
        int a0 = (t >= st) ? lsc[t - st] : 0;
        int a1 = (t + 256 >= st) ? lsc[t + 256 - st] : 0;
        __syncthreads();
        lsc[t] += a0; lsc[t + 256] += a1;
        __syncthreads();
    }
    // pass 2: stage into LDS, bucket-grouped (exclusive = lsc - lh)
    for (int i = t; i < 8192; i += 256) {
        int e = base + i;
        if (e < E) {
            int s = ei[e], d = ei[E + e];     // L2-hot re-read
            int b = d >> BSHIFT;
            int pos = lsc[b] - lh[b] + atomicAdd(&lcur[b], 1);
            sp[pos] = make_int2(s, d);
        }
    }
    __syncthreads();
    // reserve contiguous global runs per bucket
    if (t < NB && lh[t]) gb[t] = atomicAdd(&bcur[t], lh[t]);
    if (t + 256 < NB && lh[t + 256]) gb[t + 256] = atomicAdd(&bcur[t + 256], lh[t + 256]);
    __syncthreads();
    int tot = lsc[511];
    for (int i = t; i < tot; i += 256) {
        int2 p = sp[i];
        int b = p.y >> BSHIFT;
        pairs[gb[b] + (i - (lsc[b] - lh[b]))] = p;
    }
}

// one block per bucket: local counting sort -> csr window + off
__global__ __launch_bounds__(256)
void k_bcsr(const int2* __restrict__ pairs, const int* __restrict__ bbase,
            int* __restrict__ csr, int* __restrict__ off, int N, int NB, int E) {
    __shared__ int2 sp[BCAP];                 // 48 KB
    __shared__ int lh[256], lsc[256], lcur[256];
    int t = threadIdx.x;
    int b = blockIdx.x;
    int base = bbase[b];
    int m = bbase[b + 1] - base;
    int v0 = b << BSHIFT;
    lh[t] = 0; lcur[t] = 0;
    __syncthreads();
    bool fits = (m <= BCAP);
    for (int i = t; i < m; i += 256) {
        int2 p = pairs[base + i];
        if (fits) sp[i] = p;
        atomicAdd(&lh[p.y & 255], 1);
    }
    __syncthreads();
    int myv = lh[t];
    lsc[t] = myv;
    __syncthreads();
    for (int st = 1; st < 256; st <<= 1) {
        int a = (t >= st) ? lsc[t - st] : 0;
        __syncthreads();
        lsc[t] += a;
        __syncthreads();
    }
    int excl = lsc[t] - myv;
    __syncthreads();
    lsc[t] = excl;                            // exclusive scan, visible to all
    __syncthreads();
    int v = v0 + t;
    if (v < N) off[v] = base + excl;
    if (b == NB - 1 && t == 0) off[N] = E;
    for (int i = t; i < m; i += 256) {
        int2 p = fits ? sp[i] : pairs[base + i];
        int d = p.y & 255;
        int pos = lsc[d] + atomicAdd(&lcur[d], 1);
        csr[base + pos] = p.x;                // 16 KB window: L2-compact writeback
    }
}

// ---------------- Prep: MFMA-fragment-packed MLP weights (bf16 hi/lo) ----------------

__global__ void k_prep(const float* __restrict__ mW1, const float* __restrict__ mg,
                       const float* __restrict__ mbn, const float* __restrict__ mW2,
                       const float* __restrict__ mb2,
                       unsigned short* __restrict__ w1fh, unsigned short* __restrict__ w1fl,
                       unsigned short* __restrict__ w2fh, unsigned short* __restrict__ w2fl,
                       float* __restrict__ k12)
{
    int b = blockIdx.x, t = threadIdx.x;
    if (b == 0) {
        for (int idx = t; idx < 2048; idx += 256) {
            int nt = idx >> 7, rem = idx & 127;
            int kc = rem >> 6, ln = rem & 63;
#pragma unroll
            for (int i = 0; i < 8; ++i) {
                int c = kc * 32 + (ln >> 4) * 8 + i;
                int j = nt * 16 + (ln & 15);
                float v = mW1[c * 256 + j];
                unsigned short hi = f2bh(v);
                unsigned short lo = f2bh(v - bh2f(hi));
                w1fh[idx * 8 + i] = hi;
                w1fl[idx * 8 + i] = lo;
            }
        }
    } else if (b == 1) {
        for (int idx = t; idx < 2048; idx += 256) {
            int nt2 = idx >> 9, rem = idx & 511;
            int kc2 = rem >> 6, ln = rem & 63;
#pragma unroll
            for (int i = 0; i < 8; ++i) {
                int j = kc2 * 32 + (ln >> 4) * 8 + i;
                int o = nt2 * 16 + (ln & 15);
                float v = mg[j] * mW2[j * 64 + o];
                unsigned short hi = f2bh(v);
                unsigned short lo = f2bh(v - bh2f(hi));
                w2fh[idx * 8 + i] = hi;
                w2fl[idx * 8 + i] = lo;
            }
        }
    } else if (b == 2 && t < 64) {
        float a1 = 0.f, a2 = 0.f;
        for (int j = 0; j < 256; ++j) {
            a1 += mbn[j] * mW2[j * 64 + t];
            a2 += mg[j]  * mW2[j * 64 + t];
        }
        k12[t] = a1 + mb2[t];
        k12[64 + t] = a2;
    }
}

// ---------------- Layer 0 (N_IN=4), one thread per node ----------------

__global__ __launch_bounds__(256, 4)
void k_layer0(const float* __restrict__ x, float* __restrict__ hout,
              const int* __restrict__ off, const int* __restrict__ csr,
              const float* __restrict__ Wl0, const float* __restrict__ bl0,
              const float* __restrict__ Wr0, const float* __restrict__ Wres,
              const float* __restrict__ bres, const float* __restrict__ lg,
              const float* __restrict__ lb, int N)
{
    __shared__ float sWl[512], sWr[256], sWres[256], sC[256];
    int t = threadIdx.x;
    sWl[t] = Wl0[t]; sWl[256 + t] = Wl0[256 + t];
    sWr[t] = Wr0[t];
    sWres[t] = Wres[t];
    if (t < 64) { sC[t] = bl0[t]; sC[64 + t] = bres[t]; sC[128 + t] = lg[t]; sC[192 + t] = lb[t]; }
    __syncthreads();
    int v = blockIdx.x * 256 + t;
    if (v >= N) return;
    const float4* X4 = reinterpret_cast<const float4*>(x);
    float4 xv = X4[v];
    int s0 = off[v], s1 = off[v + 1];
    float4 mx = {NEG_INF, NEG_INF, NEG_INF, NEG_INF};
    float4 sm = {0.f, 0.f, 0.f, 0.f};
    for (int e = s0; e < s1; e += 4) {
        int last = s1 - 1;
        int i0 = csr[e];
        int i1 = csr[min(e + 1, last)];
        int i2 = csr[min(e + 2, last)];
        int i3 = csr[min(e + 3, last)];
        float4 a0 = X4[i0], a1 = X4[i1], a2 = X4[i2], a3 = X4[i3];
        mx.x = fmaxf(fmaxf(fmaxf(mx.x, a0.x), fmaxf(a1.x, a2.x)), a3.x);
        mx.y = fmaxf(fmaxf(fmaxf(mx.y, a0.y), fmaxf(a1.y, a2.y)), a3.y);
        mx.z = fmaxf(fmaxf(fmaxf(mx.z, a0.z), fmaxf(a1.z, a2.z)), a3.z);
        mx.w = fmaxf(fmaxf(fmaxf(mx.w, a0.w), fmaxf(a1.w, a2.w)), a3.w);
        bool o1 = e + 1 < s1, o2 = e + 2 < s1, o3 = e + 3 < s1;
        sm.x += a0.x + (o1 ? a1.x : 0.f) + (o2 ? a2.x : 0.f) + (o3 ? a3.x : 0.f);
        sm.y += a0.y + (o1 ? a1.y : 0.f) + (o2 ? a2.y : 0.f) + (o3 ? a3.y : 0.f);
        sm.z += a0.z + (o1 ? a1.z : 0.f) + (o2 ? a2.z : 0.f) + (o3 ? a3.z : 0.f);
        sm.w += a0.w + (o1 ? a1.w : 0.f) + (o2 ? a2.w : 0.f) + (o3 ? a3.w : 0.f);
    }
    int deg = s1 - s0;
    if (deg == 0) { mx.x = 0.f; mx.y = 0.f; mx.z = 0.f; mx.w = 0.f; }
    float inv = 1.f / (float)max(deg, 1);
    float4 mn = {sm.x * inv, sm.y * inv, sm.z * inv, sm.w * inv};
    float a[64];
    float acc1 = 0.f, acc2 = 0.f;
#pragma unroll
    for (int k = 0; k < 64; ++k) {
        float tv = sC[k]
            + mx.x * sWl[k]       + mx.y * sWl[64 + k]  + mx.z * sWl[128 + k] + mx.w * sWl[192 + k]
            + mn.x * sWl[256 + k] + mn.y * sWl[320 + k] + mn.z * sWl[384 + k] + mn.w * sWl[448 + k]
            + xv.x * sWr[k]       + xv.y * sWr[64 + k]  + xv.z * sWr[128 + k] + xv.w * sWr[192 + k];
        a[k] = tv; acc1 += tv; acc2 += tv * tv;
    }
    float mu = acc1 * (1.f / 64.f);
    float var = acc2 * (1.f / 64.f) - mu * mu;
    float rs = rsqrtf(var + 1e-5f);
    float* orow = hout + (size_t)v * 64;
#pragma unroll
    for (int k = 0; k < 64; ++k) {
        float res = sC[64 + k] + xv.x * sWres[k] + xv.y * sWres[64 + k]
                  + xv.z * sWres[128 + k] + xv.w * sWres[192 + k];
        float y = (a[k] - mu) * rs * sC[128 + k] + sC[192 + k] + res;
        orow[k] = silu_f(y);
    }
}

// ---------------- k_agg: gather + aggregate only (high occupancy) ----------------

__global__ __launch_bounds__(256, 8)
void k_agg(const float* __restrict__ hin, float* __restrict__ aggws,
           const int* __restrict__ off, const int* __restrict__ csr, int N)
{
    int lane = threadIdx.x & 63;
    int gw = (blockIdx.x * blockDim.x + threadIdx.x) >> 6;
    int nw = (gridDim.x * blockDim.x) >> 6;
    for (int v = gw; v < N; v += nw) {
        int s0 = off[v], s1 = off[v + 1];
        float mx = NEG_INF, sm = 0.f;
        for (int cb = s0; cb < s1; cb += 64) {
            int cdeg = min(64, s1 - cb);
            int idxv = csr[min(cb + lane, s1 - 1)];
            for (int b = 0; b < cdeg; b += 8) {
                float vv[8];
#pragma unroll
                for (int u = 0; u < 8; ++u) {
                    int iu = __builtin_amdgcn_readlane(idxv, b + u);
                    vv[u] = hin[((size_t)iu << 6) + lane];
                }
#pragma unroll
                for (int u = 0; u < 8; ++u) {
                    mx = fmaxf(mx, vv[u]);                // dup rows don't change max
                    sm += (b + u < cdeg) ? vv[u] : 0.f;   // mask dups out of sum
                }
            }
        }
        int deg = s1 - s0;
        if (deg == 0) mx = 0.f;
        float mean = sm / (float)max(deg, 1);
        aggws[((size_t)v << 7) + lane] = mx;
        aggws[((size_t)v << 7) + 64 + lane] = mean;
    }
}

// ---------------- k_smm: matmul+LN+silu, round-4 readlane structure ----------------

__global__ __launch_bounds__(256, 2)
void k_smm(const float* __restrict__ aggws, const float* __restrict__ hin,
           float* __restrict__ hout,
           const float* __restrict__ Wl, const float* __restrict__ bl,
           const float* __restrict__ Wr, const float* __restrict__ lg,
           const float* __restrict__ lb, int N)
{
    int lane = threadIdx.x & 63;
    int gw = (blockIdx.x * blockDim.x + threadIdx.x) >> 6;
    int nw = (gridDim.x * blockDim.x) >> 6;
    float wl[128], wr[64];
#pragma unroll
    for (int c = 0; c < 128; ++c) wl[c] = Wl[c * 64 + lane];
#pragma unroll
    for (int c = 0; c < 64; ++c) wr[c] = Wr[c * 64 + lane];
    float blv = bl[lane], gv = lg[lane], bv = lb[lane];
    for (int v = gw; v < N; v += nw) {
        float mx   = aggws[((size_t)v << 7) + lane];
        float mean = aggws[((size_t)v << 7) + 64 + lane];
        float hs   = hin[((size_t)v << 6) + lane];
        float a0 = blv, a1 = 0.f, a2 = 0.f;
#pragma unroll
        for (int c = 0; c < 64; ++c) {
            a0 += rlane(mx, c) * wl[c];
            a1 += rlane(mean, c) * wl[64 + c];
            a2 += rlane(hs, c) * wr[c];
        }
        float acc = a0 + a1 + a2;
        float mu = acc;
#pragma unroll
        for (int m = 1; m < 64; m <<= 1) mu += __shfl_xor(mu, m, 64);
        mu *= (1.f / 64.f);
        float xc = acc - mu;
        float var = xc * xc;
#pragma unroll
        for (int m = 1; m < 64; m <<= 1) var += __shfl_xor(var, m, 64);
        var *= (1.f / 64.f);
        float y = xc * rsqrtf(var + 1e-5f) * gv + bv + hs;
        hout[((size_t)v << 6) + lane] = silu_f(y);
    }
}

// ---------------- k_mlpm: MFMA MLP, M-tile=64 per block, split-bf16 (3 products) ----------------

__global__ __launch_bounds__(256, 2)
void k_mlpm(const float* __restrict__ hin, float* __restrict__ hout,
            const unsigned short* __restrict__ w1fh, const unsigned short* __restrict__ w1fl,
            const unsigned short* __restrict__ w2fh, const unsigned short* __restrict__ w2fl,
            const float* __restrict__ b1, const float* __restrict__ K12, int N)
{
    __shared__ __align__(16) char lds[70656];
    float* p1 = (float*)lds;                         // [4 waves][64 nodes]
    float* p2 = (float*)(lds + 1024);
    unsigned short* hhi = (unsigned short*)(lds + 2048);   // [64][72] bf16 (phase 1)
    unsigned short* hlo = (unsigned short*)(lds + 11264);
    unsigned int* spack = (unsigned int*)(lds + 2048);     // [64][268] hi<<16|lo (phase 2)

    int t = threadIdx.x;
    int lane = t & 63, w = t >> 6, quad = lane >> 4, l15 = lane & 15;

    // ---- stage h tile -> bf16 hi/lo in LDS ----
    {
        int row = t >> 2, cq = (t & 3) * 16;
        int node0 = blockIdx.x * 64 + row;
        const float4* hr = (const float4*)(hin + (size_t)min(node0, N - 1) * 64 + cq);
        float v[16];
#pragma unroll
        for (int k = 0; k < 4; ++k) {
            float4 f = hr[k];
            v[4 * k] = f.x; v[4 * k + 1] = f.y; v[4 * k + 2] = f.z; v[4 * k + 3] = f.w;
        }
#pragma unroll
        for (int g = 0; g < 2; ++g) {
            short8 ph, pl;
#pragma unroll
            for (int i = 0; i < 8; ++i) {
                float x = v[g * 8 + i];
                unsigned short hi = f2bh(x);
                ph[i] = (short)hi;
                pl[i] = (short)f2bh(x - bh2f(hi));
            }
            int idx = row * 72 + cq + g * 8;
            *(short8*)(hhi + idx) = ph;
            *(short8*)(hlo + idx) = pl;
        }
    }
    __syncthreads();

    // ---- GEMM1: wave w covers j in [w*64, w*64+64) ----
    f32x4 acc[4][4];
#pragma unroll
    for (int mt = 0; mt < 4; ++mt)
#pragma unroll
        for (int nt = 0; nt < 4; ++nt)
            acc[mt][nt] = (f32x4){0.f, 0.f, 0.f, 0.f};
#pragma unroll
    for (int kc = 0; kc < 2; ++kc) {
        short8 ah[4], al[4];
#pragma unroll
        for (int mt = 0; mt < 4; ++mt) {
            int idx = (mt * 16 + l15) * 72 + kc * 32 + quad * 8;
            ah[mt] = *(const short8*)(hhi + idx);
            al[mt] = *(const short8*)(hlo + idx);
        }
#pragma unroll
        for (int nt = 0; nt < 4; ++nt) {
            int fo = (((w * 4 + nt) * 2 + kc) * 64 + lane) * 8;
            short8 bh_ = *(const short8*)(w1fh + fo);
            short8 bl_ = *(const short8*)(w1fl + fo);
#pragma unroll
            for (int mt = 0; mt < 4; ++mt) {
                acc[mt][nt] = __builtin_amdgcn_mfma_f32_16x16x32_bf16(ah[mt], bh_, acc[mt][nt], 0, 0, 0);
                acc[mt][nt] = __builtin_amdgcn_mfma_f32_16x16x32_bf16(al[mt], bh_, acc[mt][nt], 0, 0, 0);
                acc[mt][nt] = __builtin_amdgcn_mfma_f32_16x16x32_bf16(ah[mt], bl_, acc[mt][nt], 0, 0, 0);
            }
        }
    }

    // ---- bias + silu + LN partial stats (per node = mt*16+quad*4+r) ----
    float b1v[4];
#pragma unroll
    for (int nt = 0; nt < 4; ++nt) b1v[nt] = b1[(w * 4 + nt) * 16 + l15];
    float psum[4][4], psq[4][4];
#pragma unroll
    for (int mt = 0; mt < 4; ++mt)
#pragma unroll
        for (int r = 0; r < 4; ++r) { psum[mt][r] = 0.f; psq[mt][r] = 0.f; }
#pragma unroll
    for (int mt = 0; mt < 4; ++mt)
#pragma unroll
        for (int nt = 0; nt < 4; ++nt)
#pragma unroll
            for (int r = 0; r < 4; ++r) {
                float sv = silu_f(acc[mt][nt][r] + b1v[nt]);
                acc[mt][nt][r] = sv;
                psum[mt][r] += sv;
                psq[mt][r] += sv * sv;
            }
#pragma unroll
    for (int mt = 0; mt < 4; ++mt)
#pragma unroll
        for (int r = 0; r < 4; ++r) {
            float a = psum[mt][r], b = psq[mt][r];
#pragma unroll
            for (int m = 1; m < 16; m <<= 1) {
                a += __shfl_xor(a, m, 64);
                b += __shfl_xor(b, m, 64);
            }
            psum[mt][r] = a; psq[mt][r] = b;
        }
    if (l15 == 0) {
#pragma unroll
        for (int mt = 0; mt < 4; ++mt)
#pragma unroll
            for (int r = 0; r < 4; ++r) {
                int nl = mt * 16 + quad * 4 + r;
                p1[w * 64 + nl] = psum[mt][r];
                p2[w * 64 + nl] = psq[mt][r];
            }
    }
    __syncthreads();   // all GEMM1 LDS reads done; partials visible

    // ---- repack s (C layout) -> LDS A-layout rows, bf16 hi|lo packed ----
#pragma unroll
    for (int mt = 0; mt < 4; ++mt)
#pragma unroll
        for (int nt = 0; nt < 4; ++nt)
#pragma unroll
            for (int r = 0; r < 4; ++r) {
                float sv = acc[mt][nt][r];
                unsigned short hi = f2bh(sv);
                unsigned short lo = f2bh(sv - bh2f(hi));
                spack[(mt * 16 + quad * 4 + r) * 268 + (w * 4 + nt) * 16 + l15] =
                    (((unsigned int)hi) << 16) | (unsigned int)lo;
            }
    __syncthreads();

    // ---- GEMM2: wave w handles M-tile mt=w (nodes w*16..w*16+15), full K=256 ----
    f32x4 acc2[4];
#pragma unroll
    for (int nt2 = 0; nt2 < 4; ++nt2) acc2[nt2] = (f32x4){0.f, 0.f, 0.f, 0.f};
#pragma unroll
    for (int kc2 = 0; kc2 < 8; ++kc2) {
        int base = (w * 16 + l15) * 268 + kc2 * 32 + quad * 8;
        uint4 q0 = *(const uint4*)(spack + base);
        uint4 q1 = *(const uint4*)(spack + base + 4);
        unsigned int vv[8] = {q0.x, q0.y, q0.z, q0.w, q1.x, q1.y, q1.z, q1.w};
        short8 ah, al;
#pragma unroll
        for (int i = 0; i < 8; ++i) {
            ah[i] = (short)(vv[i] >> 16);
            al[i] = (short)(vv[i] & 0xffffu);
        }
#pragma unroll
        for (int nt2 = 0; nt2 < 4; ++nt2) {
            int fo = ((nt2 * 8 + kc2) * 64 + lane) * 8;
            short8 bh_ = *(const short8*)(w2fh + fo);
            short8 bl_ = *(const short8*)(w2fl + fo);
            acc2[nt2] = __builtin_amdgcn_mfma_f32_16x16x32_bf16(ah, bh_, acc2[nt2], 0, 0, 0);
            acc2[nt2] = __builtin_amdgcn_mfma_f32_16x16x32_bf16(al, bh_, acc2[nt2], 0, 0, 0);
            acc2[nt2] = __builtin_amdgcn_mfma_f32_16x16x32_bf16(ah, bl_, acc2[nt2], 0, 0, 0);
        }
    }

    // ---- epilogue: LN fold (K12 identity) + store ----
    float k1v[4], k2v[4];
#pragma unroll
    for (int nt2 = 0; nt2 < 4; ++nt2) {
        k1v[nt2] = K12[nt2 * 16 + l15];
        k2v[nt2] = K12[64 + nt2 * 16 + l15];
    }
#pragma unroll
    for (int r = 0; r < 4; ++r) {
        int nl = w * 16 + quad * 4 + r;
        float s1 = p1[nl] + p1[64 + nl] + p1[128 + nl] + p1[192 + nl];
        float s2 = p2[nl] + p2[64 + nl] + p2[128 + nl] + p2[192 + nl];
        float mu = s1 * (1.f / 256.f);
        float var = s2 * (1.f / 256.f) - mu * mu;
        float rs = rsqrtf(var + 1e-5f);
        float rm = rs * mu;
        int node = blockIdx.x * 64 + nl;
        if (node < N) {
#pragma unroll
            for (int nt2 = 0; nt2 < 4; ++nt2)
                hout[(size_t)node * 64 + nt2 * 16 + l15] =
                    rs * acc2[nt2][r] + k1v[nt2] - rm * k2v[nt2];
        }
    }
}

// ---------------- Readout: block per graph ----------------

__global__ __launch_bounds__(256, 2)
void k_readout(const float* __restrict__ h2, const float* __restrict__ x,
               const int* __restrict__ ptr,
               const float* __restrict__ W1, const float* __restrict__ b1,
               const float* __restrict__ lg, const float* __restrict__ lb,
               const float* __restrict__ W2, const float* __restrict__ b2,
               float* __restrict__ out)
{
    __shared__ float f[196];
    __shared__ float sred[4][64];
    __shared__ float mred[4][64];
    __shared__ float lred[8];
    __shared__ float pr[4][4];
    int t = threadIdx.x, lane = t & 63, w = t >> 6;
    int g = blockIdx.x;
    int s0 = ptr[g], s1 = ptr[g + 1];
    float sm = 0.f, mx = NEG_INF;
    for (int r = s0 + w; r < s1; r += 4) {
        float v = h2[(size_t)r * 64 + lane];
        sm += v; mx = fmaxf(mx, v);
    }
    sred[w][lane] = sm; mred[w][lane] = mx;
    __syncthreads();
    if (w == 0) {
        float ssum = sred[0][lane] + sred[1][lane] + sred[2][lane] + sred[3][lane];
        float smax = fmaxf(fmaxf(mred[0][lane], mred[1][lane]),
                           fmaxf(mred[2][lane], mred[3][lane]));
        int cnt = s1 - s0;
        if (cnt == 0) smax = 0.f;
        f[lane] = ssum / (float)max(cnt, 1);
        f[64 + lane] = smax;
        f[128 + lane] = ssum;
    }
    if (t < 4) f[192 + t] = x[(size_t)s0 * 4 + t];
    __syncthreads();
    float o = b1[t];
    for (int c = 0; c < 196; ++c) o += f[c] * W1[c * 256 + t];
    o = silu_f(o);
    float s = o, s2v = o * o;
#pragma unroll
    for (int m = 1; m < 64; m <<= 1) { s += __shfl_xor(s, m, 64); s2v += __shfl_xor(s2v, m, 64); }
    if (lane == 0) { lred[w] = s; lred[4 + w] = s2v; }
    __syncthreads();
    float tot = lred[0] + lred[1] + lred[2] + lred[3];
    float tot2 = lred[4] + lred[5] + lred[6] + lred[7];
    float mu = tot * (1.f / 256.f);
    float var = tot2 * (1.f / 256.f) - mu * mu;
    float u = (o - mu) * rsqrtf(var + 1e-5f) * lg[t] + lb[t];
    float4 w2r = reinterpret_cast<const float4*>(W2)[t];
    float p0 = u * w2r.x, p1 = u * w2r.y, p2 = u * w2r.z, p3 = u * w2r.w;
#pragma unroll
    for (int m = 1; m < 64; m <<= 1) {
        p0 += __shfl_xor(p0, m, 64); p1 += __shfl_xor(p1, m, 64);
        p2 += __shfl_xor(p2, m, 64); p3 += __shfl_xor(p3, m, 64);
    }
    if (lane == 0) { pr[w][0] = p0; pr[w][1] = p1; pr[w][2] = p2; pr[w][3] = p3; }
    __syncthreads();
    if (t < 4) out[g * 4 + t] = pr[0][t] + pr[1][t] + pr[2][t] + pr[3][t] + b2[t];
}

// ---------------- launch ----------------

extern "C" void kernel_launch(void* const* d_in, const int* in_sizes, int n_in,
                              void* d_out, int out_size, void* d_ws, size_t ws_size,
                              hipStream_t stream)
{
    const float* x    = (const float*)d_in[0];
    const int*   ei   = (const int*)d_in[1];
    const int*   ptr  = (const int*)d_in[3];
    const float* Wl0  = (const float*)d_in[4];
    const float* bl0  = (const float*)d_in[5];
    const float* Wr0  = (const float*)d_in[6];
    const float* Wl   = (const float*)d_in[7];
    const float* bl   = (const float*)d_in[8];
    const float* Wr   = (const float*)d_in[9];
    const float* Wres = (const float*)d_in[10];
    const float* bres = (const float*)d_in[11];
    const float* lng  = (const float*)d_in[12];
    const float* lnb  = (const float*)d_in[13];
    const float* mW1  = (const float*)d_in[14];
    const float* mb1  = (const float*)d_in[15];
    const float* mg   = (const float*)d_in[16];
    const float* mbn  = (const float*)d_in[17];
    const float* mW2  = (const float*)d_in[18];
    const float* mb2  = (const float*)d_in[19];
    const float* rW1  = (const float*)d_in[20];
    const float* rb1  = (const float*)d_in[21];
    const float* rg   = (const float*)d_in[22];
    const float* rbn  = (const float*)d_in[23];
    const float* rW2  = (const float*)d_in[24];
    const float* rb2  = (const float*)d_in[25];
    float* out = (float*)d_out;

    int N = in_sizes[0] / 4;
    int E = in_sizes[1] / 2;
    int NG = in_sizes[3] - 1;
    int nchunk = (N + 255) / 256;
    int nblkm  = (N + 63) / 64;
    int NB     = (N + 255) >> BSHIFT;         // 256-node buckets
    int nbh    = (E + 8191) / 8192;

    char* ws = (char*)d_ws;
    size_t o = 0;
    auto alloc = [&](size_t bytes) -> void* {
        void* p = ws + o;
        o += (bytes + 255) & ~(size_t)255;
        return p;
    };
    int*   off   = (int*)alloc((size_t)(N + 1) * 4);
    int*   btot  = (int*)alloc((size_t)NB * 4);
    int*   bbase = (int*)alloc((size_t)(NB + 1) * 4);
    int*   bcur  = (int*)alloc((size_t)NB * 4);
    int*   csr   = (int*)alloc((size_t)E * 4);
    int2*  pairs = (int2*)alloc((size_t)E * 8);
    float* ha    = (float*)alloc((size_t)N * 64 * 4);
    float* hb    = (float*)alloc((size_t)N * 64 * 4);
    float* aggws = (float*)alloc((size_t)N * 128 * 4);
    unsigned short* w1fh = (unsigned short*)alloc(16384 * 2);
    unsigned short* w1fl = (unsigned short*)alloc(16384 * 2);
    unsigned short* w2fh = (unsigned short*)alloc(16384 * 2);
    unsigned short* w2fl = (unsigned short*)alloc(16384 * 2);
    float* k12   = (float*)alloc(128 * 4);

    hipMemsetAsync(btot, 0, (size_t)NB * 4, stream);
    k_prep<<<3, 256, 0, stream>>>(mW1, mg, mbn, mW2, mb2, w1fh, w1fl, w2fh, w2fl, k12);
    k_bhist<<<nbh, 256, 0, stream>>>(ei, btot, E, NB);
    k_bscan<<<1, 256, 0, stream>>>(btot, bbase, bcur, NB, E);
    k_bscatter<<<nbh, 256, 0, stream>>>(ei, bcur, pairs, E, NB);
    k_bcsr<<<NB, 256, 0, stream>>>(pairs, bbase, csr, off, N, NB, E);

    k_layer0<<<nchunk, 256, 0, stream>>>(x, ha, off, csr, Wl0, bl0, Wr0, Wres, bres, lng, lnb, N);

    k_agg<<<2048, 256, 0, stream>>>(ha, aggws, off, csr, N);
    k_smm<<<1024, 256, 0, stream>>>(aggws, ha, hb, Wl,                bl,       Wr,               lng + 64,  lnb + 64,  N);
    k_agg<<<2048, 256, 0, stream>>>(hb, aggws, off, csr, N);
    k_smm<<<1024, 256, 0, stream>>>(aggws, hb, ha, Wl + 128 * 64,     bl + 64,  Wr + 64 * 64,     lng + 128, lnb + 128, N);
    k_agg<<<2048, 256, 0, stream>>>(ha, aggws, off, csr, N);
    k_smm<<<1024, 256, 0, stream>>>(aggws, ha, hb, Wl + 2 * 128 * 64, bl + 128, Wr + 2 * 64 * 64, lng + 192, lnb + 192, N);

    k_mlpm<<<nblkm, 256, 0, stream>>>(hb, ha, w1fh, w1fl, w2fh, w2fl, mb1, k12, N);
    k_readout<<<NG, 256, 0, stream>>>(ha, x, ptr, rW1, rb1, rg, rbn, rW2, rb2, out);
}

// Round 9
// 609.067 us; speedup vs baseline: 2.3124x; 1.2373x over previous
//
#include <hip/hip_runtime.h>
#include <math.h>

#define NEG_INF (-__builtin_inff())
#define BSHIFT 8                    // 256-node buckets
#define BCAP 6144                   // k_bcsr LDS pair capacity
#define SK 200                      // padded LDS row stride (shorts) for k_smm_m

typedef __attribute__((ext_vector_type(8))) short short8;    // 8 bf16 = 4 VGPR
typedef __attribute__((ext_vector_type(4))) float f32x4;

__device__ __forceinline__ float rlane(float x, int l) {
    return __int_as_float(__builtin_amdgcn_readlane(__float_as_int(x), l));
}

__device__ __forceinline__ float silu_f(float y) {
    return y / (1.f + __expf(-y));
}

// bf16 round-to-nearest-even helpers for split-precision
__device__ __forceinline__ unsigned short f2bh(float x) {
    unsigned int u = __float_as_uint(x);
    u += 0x7fffu + ((u >> 16) & 1u);
    return (unsigned short)(u >> 16);
}
__device__ __forceinline__ float bh2f(unsigned short h) {
    return __uint_as_float(((unsigned int)h) << 16);
}

// ---------------- Bucketed CSR build (round-8, proven) ----------------

__global__ __launch_bounds__(256)
void k_bhist(const int* __restrict__ ei, int* __restrict__ btot, int E, int NB) {
    __shared__ int lh[512];
    int t = threadIdx.x;
    lh[t] = 0; lh[t + 256] = 0;
    __syncthreads();
    int base = blockIdx.x * 8192;
    for (int i = t; i < 8192; i += 256) {
        int e = base + i;
        if (e < E) atomicAdd(&lh[ei[E + e] >> BSHIFT], 1);
    }
    __syncthreads();
    if (lh[t]) atomicAdd(&btot[t], lh[t]);
    if (t + 256 < NB && lh[t + 256]) atomicAdd(&btot[t + 256], lh[t + 256]);
}

__global__ __launch_bounds__(256)
void k_bscan(const int* __restrict__ btot, int* __restrict__ bbase,
             int* __restrict__ bcur, int NB, int E) {
    __shared__ int s[512];
    int t = threadIdx.x;
    int v0 = (t < NB) ? btot[t] : 0;
    int v1 = (t + 256 < NB) ? btot[t + 256] : 0;
    s[t] = v0; s[t + 256] = v1;
    __syncthreads();
    for (int st = 1; st < 512; st <<= 1) {
        int a0 = (t >= st) ? s[t - st] : 0;
        int a1 = (t + 256 >= st) ? s[t + 256 - st] : 0;
        __syncthreads();
        s[t] += a0; s[t + 256] += a1;
        __syncthreads();
    }
    if (t < NB)       { bbase[t] = s[t] - v0;             bcur[t] = s[t] - v0; }
    if (t + 256 < NB) { bbase[t + 256] = s[t + 256] - v1; bcur[t + 256] = s[t + 256] - v1; }
    if (t == 0) bbase[NB] = E;
}

__global__ __launch_bounds__(256)
void k_bscatter(const int* __restrict__ ei, int* __restrict__ bcur,
                int2* __restrict__ pairs, int E, int NB) {
    __shared__ int2 sp[8192];
    __shared__ int lh[512], lsc[512], lcur[512], gb[512];
    int t = threadIdx.x;
    lh[t] = 0; lh[t + 256] = 0; lcur[t] = 0; lcur[t + 256] = 0;
    __syncthreads();
    int base = blockIdx.x * 8192;
    for (int i = t; i < 8192; i += 256) {
        int e = base + i;
        if (e < E) atomicAdd(&lh[ei[E + e] >> BSHIFT], 1);
    }
    __syncthreads();
    lsc[t] = lh[t]; lsc[t + 256] = lh[t + 256];
    __syncthreads();
    for (int st = 1; st < 512; st <<= 1) {
        int a0 = (t >= st) ? lsc[t - st] : 0;
        int a1 = (t + 256 >= st) ? lsc[t + 256 - st] : 0;
        __syncthreads();
        lsc[t] += a0; lsc[t + 256] += a1;
        __syncthreads();
    }
    for (int i = t; i < 8192; i += 256) {
        int e = base + i;
        if (e < E) {
            int s = ei[e], d = ei[E + e];
            int b = d >> BSHIFT;
            int pos = lsc[b] - lh[b] + atomicAdd(&lcur[b], 1);
            sp[pos] = make_int2(s, d);
        }
    }
    __syncthreads();
    if (t < NB && lh[t]) gb[t] = atomicAdd(&bcur[t], lh[t]);
    if (t + 256 < NB && lh[t + 256]) gb[t + 256] = atomicAdd(&bcur[t + 256], lh[t + 256]);
    __syncthreads();
    int tot = lsc[511];
    for (int i = t; i < tot; i += 256) {
        int2 p = sp[i];
        int b = p.y >> BSHIFT;
        pairs[gb[b] + (i - (lsc[b] - lh[b]))] = p;
    }
}

__global__ __launch_bounds__(256)
void k_bcsr(const int2* __restrict__ pairs, const int* __restrict__ bbase,
            int* __restrict__ csr, int* __restrict__ off, int N, int NB, int E) {
    __shared__ int2 sp[BCAP];
    __shared__ int lh[256], lsc[256], lcur[256];
    int t = threadIdx.x;
    int b = blockIdx.x;
    int base = bbase[b];
    int m = bbase[b + 1] - base;
    int v0 = b << BSHIFT;
    lh[t] = 0; lcur[t] = 0;
    __syncthreads();
    bool fits = (m <= BCAP);
    for (int i = t; i < m; i += 256) {
        int2 p = pairs[base + i];
        if (fits) sp[i] = p;
        atomicAdd(&lh[p.y & 255], 1);
    }
    __syncthreads();
    int myv = lh[t];
    lsc[t] = myv;
    __syncthreads();
    for (int st = 1; st < 256; st <<= 1) {
        int a = (t >= st) ? lsc[t - st] : 0;
        __syncthreads();
        lsc[t] += a;
        __syncthreads();
    }
    int excl = lsc[t] - myv;
    __syncthreads();
    lsc[t] = excl;
    __syncthreads();
    int v = v0 + t;
    if (v < N) off[v] = base + excl;
    if (b == NB - 1 && t == 0) off[N] = E;
    for (int i = t; i < m; i += 256) {
        int2 p = fits ? sp[i] : pairs[base + i];
        int d = p.y & 255;
        int pos = lsc[d] + atomicAdd(&lcur[d], 1);
        csr[base + pos] = p.x;
    }
}

// ---------------- Prep: fragment-packed weights (bf16 hi/lo) ----------------
// b=0: mlp W1   b=1: mlp g*W2   b=2: k12   b=3..5: sage layer b-3
// sage pack: wsf[((l*24 + nt*6+kc)*64 + ln)*8 + i] = W[k][o],
//   k = kc*32+(ln>>4)*8+i (k<128: Wl row, else Wr row k-128), o = nt*16+(ln&15)

__global__ void k_prep(const float* __restrict__ mW1, const float* __restrict__ mg,
                       const float* __restrict__ mbn, const float* __restrict__ mW2,
                       const float* __restrict__ mb2,
                       const float* __restrict__ Wl, const float* __restrict__ Wr,
                       unsigned short* __restrict__ w1fh, unsigned short* __restrict__ w1fl,
                       unsigned short* __restrict__ w2fh, unsigned short* __restrict__ w2fl,
                       unsigned short* __restrict__ wsfh, unsigned short* __restrict__ wsfl,
                       float* __restrict__ k12)
{
    int b = blockIdx.x, t = threadIdx.x;
    if (b == 0) {
        for (int idx = t; idx < 2048; idx += 256) {
            int nt = idx >> 7, rem = idx & 127;
            int kc = rem >> 6, ln = rem & 63;
#pragma unroll
            for (int i = 0; i < 8; ++i) {
                int c = kc * 32 + (ln >> 4) * 8 + i;
                int j = nt * 16 + (ln & 15);
                float v = mW1[c * 256 + j];
                unsigned short hi = f2bh(v);
                w1fh[idx * 8 + i] = hi;
                w1fl[idx * 8 + i] = f2bh(v - bh2f(hi));
            }
        }
    } else if (b == 1) {
        for (int idx = t; idx < 2048; idx += 256) {
            int nt2 = idx >> 9, rem = idx & 511;
            int kc2 = rem >> 6, ln = rem & 63;
#pragma unroll
            for (int i = 0; i < 8; ++i) {
                int j = kc2 * 32 + (ln >> 4) * 8 + i;
                int o = nt2 * 16 + (ln & 15);
                float v = mg[j] * mW2[j * 64 + o];
                unsigned short hi = f2bh(v);
                w2fh[idx * 8 + i] = hi;
                w2fl[idx * 8 + i] = f2bh(v - bh2f(hi));
            }
        }
    } else if (b == 2 && t < 64) {
        float a1 = 0.f, a2 = 0.f;
        for (int j = 0; j < 256; ++j) {
            a1 += mbn[j] * mW2[j * 64 + t];
            a2 += mg[j]  * mW2[j * 64 + t];
        }
        k12[t] = a1 + mb2[t];
        k12[64 + t] = a2;
    } else if (b >= 3 && b < 6) {
        int l = b - 3;
        for (int idx = t; idx < 1536; idx += 256) {
            int tile = idx >> 6, ln = idx & 63;
            int nt = tile / 6, kc = tile % 6;
#pragma unroll
            for (int i = 0; i < 8; ++i) {
                int k = kc * 32 + (ln >> 4) * 8 + i;
                int o = nt * 16 + (ln & 15);
                float v = (k < 128) ? Wl[((l * 128) + k) * 64 + o]
                                    : Wr[((l * 64) + (k - 128)) * 64 + o];
                unsigned short hi = f2bh(v);
                wsfh[((l * 24 + tile) * 64 + ln) * 8 + i] = hi;
                wsfl[((l * 24 + tile) * 64 + ln) * 8 + i] = f2bh(v - bh2f(hi));
            }
        }
    }
}

// ---------------- Layer 0 (N_IN=4), one thread per node ----------------

__global__ __launch_bounds__(256, 4)
void k_layer0(const float* __restrict__ x, float* __restrict__ hout,
              const int* __restrict__ off, const int* __restrict__ csr,
              const float* __restrict__ Wl0, const float* __restrict__ bl0,
              const float* __restrict__ Wr0, const float* __restrict__ Wres,
              const float* __restrict__ bres, const float* __restrict__ lg,
              const float* __restrict__ lb, int N)
{
    __shared__ float sWl[512], sWr[256], sWres[256], sC[256];
    int t = threadIdx.x;
    sWl[t] = Wl0[t]; sWl[256 + t] = Wl0[256 + t];
    sWr[t] = Wr0[t];
    sWres[t] = Wres[t];
    if (t < 64) { sC[t] = bl0[t]; sC[64 + t] = bres[t]; sC[128 + t] = lg[t]; sC[192 + t] = lb[t]; }
    __syncthreads();
    int v = blockIdx.x * 256 + t;
    if (v >= N) return;
    const float4* X4 = reinterpret_cast<const float4*>(x);
    float4 xv = X4[v];
    int s0 = off[v], s1 = off[v + 1];
    float4 mx = {NEG_INF, NEG_INF, NEG_INF, NEG_INF};
    float4 sm = {0.f, 0.f, 0.f, 0.f};
    for (int e = s0; e < s1; e += 4) {
        int last = s1 - 1;
        int i0 = csr[e];
        int i1 = csr[min(e + 1, last)];
        int i2 = csr[min(e + 2, last)];
        int i3 = csr[min(e + 3, last)];
        float4 a0 = X4[i0], a1 = X4[i1], a2 = X4[i2], a3 = X4[i3];
        mx.x = fmaxf(fmaxf(fmaxf(mx.x, a0.x), fmaxf(a1.x, a2.x)), a3.x);
        mx.y = fmaxf(fmaxf(fmaxf(mx.y, a0.y), fmaxf(a1.y, a2.y)), a3.y);
        mx.z = fmaxf(fmaxf(fmaxf(mx.z, a0.z), fmaxf(a1.z, a2.z)), a3.z);
        mx.w = fmaxf(fmaxf(fmaxf(mx.w, a0.w), fmaxf(a1.w, a2.w)), a3.w);
        bool o1 = e + 1 < s1, o2 = e + 2 < s1, o3 = e + 3 < s1;
        sm.x += a0.x + (o1 ? a1.x : 0.f) + (o2 ? a2.x : 0.f) + (o3 ? a3.x : 0.f);
        sm.y += a0.y + (o1 ? a1.y : 0.f) + (o2 ? a2.y : 0.f) + (o3 ? a3.y : 0.f);
        sm.z += a0.z + (o1 ? a1.z : 0.f) + (o2 ? a2.z : 0.f) + (o3 ? a3.z : 0.f);
        sm.w += a0.w + (o1 ? a1.w : 0.f) + (o2 ? a2.w : 0.f) + (o3 ? a3.w : 0.f);
    }
    int deg = s1 - s0;
    if (deg == 0) { mx.x = 0.f; mx.y = 0.f; mx.z = 0.f; mx.w = 0.f; }
    float inv = 1.f / (float)max(deg, 1);
    float4 mn = {sm.x * inv, sm.y * inv, sm.z * inv, sm.w * inv};
    float a[64];
    float acc1 = 0.f, acc2 = 0.f;
#pragma unroll
    for (int k = 0; k < 64; ++k) {
        float tv = sC[k]
            + mx.x * sWl[k]       + mx.y * sWl[64 + k]  + mx.z * sWl[128 + k] + mx.w * sWl[192 + k]
            + mn.x * sWl[256 + k] + mn.y * sWl[320 + k] + mn.z * sWl[384 + k] + mn.w * sWl[448 + k]
            + xv.x * sWr[k]       + xv.y * sWr[64 + k]  + xv.z * sWr[128 + k] + xv.w * sWr[192 + k];
        a[k] = tv; acc1 += tv; acc2 += tv * tv;
    }
    float mu = acc1 * (1.f / 64.f);
    float var = acc2 * (1.f / 64.f) - mu * mu;
    float rs = rsqrtf(var + 1e-5f);
    float* orow = hout + (size_t)v * 64;
#pragma unroll
    for (int k = 0; k < 64; ++k) {
        float res = sC[64 + k] + xv.x * sWres[k] + xv.y * sWres[64 + k]
                  + xv.z * sWres[128 + k] + xv.w * sWres[192 + k];
        float y = (a[k] - mu) * rs * sC[128 + k] + sC[192 + k] + res;
        orow[k] = silu_f(y);
    }
}

// ---------------- k_agg: gather + aggregate only (high occupancy) ----------------

__global__ __launch_bounds__(256, 8)
void k_agg(const float* __restrict__ hin, float* __restrict__ aggws,
           const int* __restrict__ off, const int* __restrict__ csr, int N)
{
    int lane = threadIdx.x & 63;
    int gw = (blockIdx.x * blockDim.x + threadIdx.x) >> 6;
    int nw = (gridDim.x * blockDim.x) >> 6;
    for (int v = gw; v < N; v += nw) {
        int s0 = off[v], s1 = off[v + 1];
        float mx = NEG_INF, sm = 0.f;
        for (int cb = s0; cb < s1; cb += 64) {
            int cdeg = min(64, s1 - cb);
            int idxv = csr[min(cb + lane, s1 - 1)];
            for (int b = 0; b < cdeg; b += 8) {
                float vv[8];
#pragma unroll
                for (int u = 0; u < 8; ++u) {
                    int iu = __builtin_amdgcn_readlane(idxv, b + u);
                    vv[u] = hin[((size_t)iu << 6) + lane];
                }
#pragma unroll
                for (int u = 0; u < 8; ++u) {
                    mx = fmaxf(mx, vv[u]);
                    sm += (b + u < cdeg) ? vv[u] : 0.f;
                }
            }
        }
        int deg = s1 - s0;
        if (deg == 0) mx = 0.f;
        float mean = sm / (float)max(deg, 1);
        aggws[((size_t)v << 7) + lane] = mx;
        aggws[((size_t)v << 7) + 64 + lane] = mean;
    }
}

// ---------------- k_smm_m: MFMA SAGE matmul+LN+silu (M-tile=64/block) ----------------
// t = [max|mean|h](K=192) @ W(192x64) + bl; out = silu(LN(t)*g + b + h)
// LN is quad-local in C-layout: node = w*16+quad*4+r lives in the quad's 16 lanes.

__global__ __launch_bounds__(256, 2)
void k_smm_m(const float* __restrict__ aggws, const float* __restrict__ hin,
             float* __restrict__ hout,
             const unsigned short* __restrict__ wfh, const unsigned short* __restrict__ wfl,
             const float* __restrict__ bl, const float* __restrict__ lg,
             const float* __restrict__ lb, int N)
{
    __shared__ __align__(16) unsigned short shi[64 * SK];   // 25.6 KB
    __shared__ __align__(16) unsigned short slo[64 * SK];
    int t = threadIdx.x;
    int lane = t & 63, w = t >> 6, quad = lane >> 4, l15 = lane & 15;

    // ---- stage [agg(128)|h(64)] rows -> bf16 hi/lo ----
    {
        int row = t >> 2, seg = t & 3;           // 4 threads/row, 48 cols each
        int node = min(blockIdx.x * 64 + row, N - 1);
        const float4* ar = (const float4*)(aggws + ((size_t)node << 7));
        const float4* hr = (const float4*)(hin + ((size_t)node << 6));
        float v[48];
#pragma unroll
        for (int q = 0; q < 12; ++q) {
            int c = seg * 48 + q * 4;
            float4 f = (c < 128) ? ar[c >> 2] : hr[(c - 128) >> 2];
            v[q * 4] = f.x; v[q * 4 + 1] = f.y; v[q * 4 + 2] = f.z; v[q * 4 + 3] = f.w;
        }
#pragma unroll
        for (int g = 0; g < 6; ++g) {
            short8 ph, pl;
#pragma unroll
            for (int i = 0; i < 8; ++i) {
                float x = v[g * 8 + i];
                unsigned short hi = f2bh(x);
                ph[i] = (short)hi;
                pl[i] = (short)f2bh(x - bh2f(hi));
            }
            int idx = row * SK + seg * 48 + g * 8;
            *(short8*)(shi + idx) = ph;
            *(short8*)(slo + idx) = pl;
        }
    }
    __syncthreads();

    // ---- GEMM: wave w = M-tile w (16 nodes), nt 0..3, K=192 ----
    f32x4 acc[4];
#pragma unroll
    for (int nt = 0; nt < 4; ++nt) acc[nt] = (f32x4){0.f, 0.f, 0.f, 0.f};
#pragma unroll
    for (int kc = 0; kc < 6; ++kc) {
        int idx = (w * 16 + l15) * SK + kc * 32 + quad * 8;
        short8 ah = *(const short8*)(shi + idx);
        short8 al = *(const short8*)(slo + idx);
#pragma unroll
        for (int nt = 0; nt < 4; ++nt) {
            int fo = ((nt * 6 + kc) * 64 + lane) * 8;
            short8 bh_ = *(const short8*)(wfh + fo);
            short8 bl_ = *(const short8*)(wfl + fo);
            acc[nt] = __builtin_amdgcn_mfma_f32_16x16x32_bf16(ah, bh_, acc[nt], 0, 0, 0);
            acc[nt] = __builtin_amdgcn_mfma_f32_16x16x32_bf16(al, bh_, acc[nt], 0, 0, 0);
            acc[nt] = __builtin_amdgcn_mfma_f32_16x16x32_bf16(ah, bl_, acc[nt], 0, 0, 0);
        }
    }

    // ---- bias + quad-local LN + residual + silu + store ----
    float blv[4], gv[4], bv[4];
#pragma unroll
    for (int nt = 0; nt < 4; ++nt) {
        int ch = nt * 16 + l15;
        blv[nt] = bl[ch]; gv[nt] = lg[ch]; bv[nt] = lb[ch];
    }
    float ps[4], pq[4];
#pragma unroll
    for (int r = 0; r < 4; ++r) { ps[r] = 0.f; pq[r] = 0.f; }
#pragma unroll
    for (int nt = 0; nt < 4; ++nt)
#pragma unroll
        for (int r = 0; r < 4; ++r) {
            float tv = acc[nt][r] + blv[nt];
            acc[nt][r] = tv;
            ps[r] += tv; pq[r] += tv * tv;
        }
#pragma unroll
    for (int r = 0; r < 4; ++r) {
        float a = ps[r], b = pq[r];
#pragma unroll
        for (int m = 1; m < 16; m <<= 1) {
            a += __shfl_xor(a, m, 64);
            b += __shfl_xor(b, m, 64);
        }
        ps[r] = a; pq[r] = b;
    }
#pragma unroll
    for (int r = 0; r < 4; ++r) {
        int node = blockIdx.x * 64 + w * 16 + quad * 4 + r;
        float mu = ps[r] * (1.f / 64.f);
        float var = pq[r] * (1.f / 64.f) - mu * mu;
        float rs = rsqrtf(var + 1e-5f);
        if (node < N) {
#pragma unroll
            for (int nt = 0; nt < 4; ++nt) {
                float hs = hin[(size_t)node * 64 + nt * 16 + l15];   // L2-hot
                float y = (acc[nt][r] - mu) * rs * gv[nt] + bv[nt] + hs;
                hout[(size_t)node * 64 + nt * 16 + l15] = silu_f(y);
            }
        }
    }
}

// ---------------- k_mlpm: MFMA MLP (round-7, proven) ----------------

__global__ __launch_bounds__(256, 2)
void k_mlpm(const float* __restrict__ hin, float* __restrict__ hout,
            const unsigned short* __restrict__ w1fh, const unsigned short* __restrict__ w1fl,
            const unsigned short* __restrict__ w2fh, const unsigned short* __restrict__ w2fl,
            const float* __restrict__ b1, const float* __restrict__ K12, int N)
{
    __shared__ __align__(16) char lds[70656];
    float* p1 = (float*)lds;
    float* p2 = (float*)(lds + 1024);
    unsigned short* hhi = (unsigned short*)(lds + 2048);
    unsigned short* hlo = (unsigned short*)(lds + 11264);
    unsigned int* spack = (unsigned int*)(lds + 2048);

    int t = threadIdx.x;
    int lane = t & 63, w = t >> 6, quad = lane >> 4, l15 = lane & 15;

    {
        int row = t >> 2, cq = (t & 3) * 16;
        int node0 = blockIdx.x * 64 + row;
        const float4* hr = (const float4*)(hin + (size_t)min(node0, N - 1) * 64 + cq);
        float v[16];
#pragma unroll
        for (int k = 0; k < 4; ++k) {
            float4 f = hr[k];
            v[4 * k] = f.x; v[4 * k + 1] = f.y; v[4 * k + 2] = f.z; v[4 * k + 3] = f.w;
        }
#pragma unroll
        for (int g = 0; g < 2; ++g) {
            short8 ph, pl;
#pragma unroll
            for (int i = 0; i < 8; ++i) {
                float x = v[g * 8 + i];
                unsigned short hi = f2bh(x);
                ph[i] = (short)hi;
                pl[i] = (short)f2bh(x - bh2f(hi));
            }
            int idx = row * 72 + cq + g * 8;
            *(short8*)(hhi + idx) = ph;
            *(short8*)(hlo + idx) = pl;
        }
    }
    __syncthreads();

    f32x4 acc[4][4];
#pragma unroll
    for (int mt = 0; mt < 4; ++mt)
#pragma unroll
        for (int nt = 0; nt < 4; ++nt)
            acc[mt][nt] = (f32x4){0.f, 0.f, 0.f, 0.f};
#pragma unroll
    for (int kc = 0; kc < 2; ++kc) {
        short8 ah[4], al[4];
#pragma unroll
        for (int mt = 0; mt < 4; ++mt) {
            int idx = (mt * 16 + l15) * 72 + kc * 32 + quad * 8;
            ah[mt] = *(const short8*)(hhi + idx);
            al[mt] = *(const short8*)(hlo + idx);
        }
#pragma unroll
        for (int nt = 0; nt < 4; ++nt) {
            int fo = (((w * 4 + nt) * 2 + kc) * 64 + lane) * 8;
            short8 bh_ = *(const short8*)(w1fh + fo);
            short8 bl_ = *(const short8*)(w1fl + fo);
#pragma unroll
            for (int mt = 0; mt < 4; ++mt) {
                acc[mt][nt] = __builtin_amdgcn_mfma_f32_16x16x32_bf16(ah[mt], bh_, acc[mt][nt], 0, 0, 0);
                acc[mt][nt] = __builtin_amdgcn_mfma_f32_16x16x32_bf16(al[mt], bh_, acc[mt][nt], 0, 0, 0);
                acc[mt][nt] = __builtin_amdgcn_mfma_f32_16x16x32_bf16(ah[mt], bl_, acc[mt][nt], 0, 0, 0);
            }
        }
    }

    float b1v[4];
#pragma unroll
    for (int nt = 0; nt < 4; ++nt) b1v[nt] = b1[(w * 4 + nt) * 16 + l15];
    float psum[4][4], psq[4][4];
#pragma unroll
    for (int mt = 0; mt < 4; ++mt)
#pragma unroll
        for (int r = 0; r < 4; ++r) { psum[mt][r] = 0.f; psq[mt][r] = 0.f; }
#pragma unroll
    for (int mt = 0; mt < 4; ++mt)
#pragma unroll
        for (int nt = 0; nt < 4; ++nt)
#pragma unroll
            for (int r = 0; r < 4; ++r) {
                float sv = silu_f(acc[mt][nt][r] + b1v[nt]);
                acc[mt][nt][r] = sv;
                psum[mt][r] += sv;
                psq[mt][r] += sv * sv;
            }
#pragma unroll
    for (int mt = 0; mt < 4; ++mt)
#pragma unroll
        for (int r = 0; r < 4; ++r) {
            float a = psum[mt][r], b = psq[mt][r];
#pragma unroll
            for (int m = 1; m < 16; m <<= 1) {
                a += __shfl_xor(a, m, 64);
                b += __shfl_xor(b, m, 64);
            }
            psum[mt][r] = a; psq[mt][r] = b;
        }
    if (l15 == 0) {
#pragma unroll
        for (int mt = 0; mt < 4; ++mt)
#pragma unroll
            for (int r = 0; r < 4; ++r) {
                int nl = mt * 16 + quad * 4 + r;
                p1[w * 64 + nl] = psum[mt][r];
                p2[w * 64 + nl] = psq[mt][r];
            }
    }
    __syncthreads();

#pragma unroll
    for (int mt = 0; mt < 4; ++mt)
#pragma unroll
        for (int nt = 0; nt < 4; ++nt)
#pragma unroll
            for (int r = 0; r < 4; ++r) {
                float sv = acc[mt][nt][r];
                unsigned short hi = f2bh(sv);
                unsigned short lo = f2bh(sv - bh2f(hi));
                spack[(mt * 16 + quad * 4 + r) * 268 + (w * 4 + nt) * 16 + l15] =
                    (((unsigned int)hi) << 16) | (unsigned int)lo;
            }
    __syncthreads();

    f32x4 acc2[4];
#pragma unroll
    for (int nt2 = 0; nt2 < 4; ++nt2) acc2[nt2] = (f32x4){0.f, 0.f, 0.f, 0.f};
#pragma unroll
    for (int kc2 = 0; kc2 < 8; ++kc2) {
        int base = (w * 16 + l15) * 268 + kc2 * 32 + quad * 8;
        uint4 q0 = *(const uint4*)(spack + base);
        uint4 q1 = *(const uint4*)(spack + base + 4);
        unsigned int vv[8] = {q0.x, q0.y, q0.z, q0.w, q1.x, q1.y, q1.z, q1.w};
        short8 ah, al;
#pragma unroll
        for (int i = 0; i < 8; ++i) {
            ah[i] = (short)(vv[i] >> 16);
            al[i] = (short)(vv[i] & 0xffffu);
        }
#pragma unroll
        for (int nt2 = 0; nt2 < 4; ++nt2) {
            int fo = ((nt2 * 8 + kc2) * 64 + lane) * 8;
            short8 bh_ = *(const short8*)(w2fh + fo);
            short8 bl_ = *(const short8*)(w2fl + fo);
            acc2[nt2] = __builtin_amdgcn_mfma_f32_16x16x32_bf16(ah, bh_, acc2[nt2], 0, 0, 0);
            acc2[nt2] = __builtin_amdgcn_mfma_f32_16x16x32_bf16(al, bh_, acc2[nt2], 0, 0, 0);
            acc2[nt2] = __builtin_amdgcn_mfma_f32_16x16x32_bf16(ah, bl_, acc2[nt2], 0, 0, 0);
        }
    }

    float k1v[4], k2v[4];
#pragma unroll
    for (int nt2 = 0; nt2 < 4; ++nt2) {
        k1v[nt2] = K12[nt2 * 16 + l15];
        k2v[nt2] = K12[64 + nt2 * 16 + l15];
    }
#pragma unroll
    for (int r = 0; r < 4; ++r) {
        int nl = w * 16 + quad * 4 + r;
        float s1 = p1[nl] + p1[64 + nl] + p1[128 + nl] + p1[192 + nl];
        float s2 = p2[nl] + p2[64 + nl] + p2[128 + nl] + p2[192 + nl];
        float mu = s1 * (1.f / 256.f);
        float var = s2 * (1.f / 256.f) - mu * mu;
        float rs = rsqrtf(var + 1e-5f);
        float rm = rs * mu;
        int node = blockIdx.x * 64 + nl;
        if (node < N) {
#pragma unroll
            for (int nt2 = 0; nt2 < 4; ++nt2)
                hout[(size_t)node * 64 + nt2 * 16 + l15] =
                    rs * acc2[nt2][r] + k1v[nt2] - rm * k2v[nt2];
        }
    }
}

// ---------------- Readout: block per graph ----------------

__global__ __launch_bounds__(256, 2)
void k_readout(const float* __restrict__ h2, const float* __restrict__ x,
               const int* __restrict__ ptr,
               const float* __restrict__ W1, const float* __restrict__ b1,
               const float* __restrict__ lg, const float* __restrict__ lb,
               const float* __restrict__ W2, const float* __restrict__ b2,
               float* __restrict__ out)
{
    __shared__ float f[196];
    __shared__ float sred[4][64];
    __shared__ float mred[4][64];
    __shared__ float lred[8];
    __shared__ float pr[4][4];
    int t = threadIdx.x, lane = t & 63, w = t >> 6;
    int g = blockIdx.x;
    int s0 = ptr[g], s1 = ptr[g + 1];
    float sm = 0.f, mx = NEG_INF;
    for (int r = s0 + w; r < s1; r += 4) {
        float v = h2[(size_t)r * 64 + lane];
        sm += v; mx = fmaxf(mx, v);
    }
    sred[w][lane] = sm; mred[w][lane] = mx;
    __syncthreads();
    if (w == 0) {
        float ssum = sred[0][lane] + sred[1][lane] + sred[2][lane] + sred[3][lane];
        float smax = fmaxf(fmaxf(mred[0][lane], mred[1][lane]),
                           fmaxf(mred[2][lane], mred[3][lane]));
        int cnt = s1 - s0;
        if (cnt == 0) smax = 0.f;
        f[lane] = ssum / (float)max(cnt, 1);
        f[64 + lane] = smax;
        f[128 + lane] = ssum;
    }
    if (t < 4) f[192 + t] = x[(size_t)s0 * 4 + t];
    __syncthreads();
    float o = b1[t];
    for (int c = 0; c < 196; ++c) o += f[c] * W1[c * 256 + t];
    o = silu_f(o);
    float s = o, s2v = o * o;
#pragma unroll
    for (int m = 1; m < 64; m <<= 1) { s += __shfl_xor(s, m, 64); s2v += __shfl_xor(s2v, m, 64); }
    if (lane == 0) { lred[w] = s; lred[4 + w] = s2v; }
    __syncthreads();
    float tot = lred[0] + lred[1] + lred[2] + lred[3];
    float tot2 = lred[4] + lred[5] + lred[6] + lred[7];
    float mu = tot * (1.f / 256.f);
    float var = tot2 * (1.f / 256.f) - mu * mu;
    float u = (o - mu) * rsqrtf(var + 1e-5f) * lg[t] + lb[t];
    float4 w2r = reinterpret_cast<const float4*>(W2)[t];
    float p0 = u * w2r.x, p1 = u * w2r.y, p2 = u * w2r.z, p3 = u * w2r.w;
#pragma unroll
    for (int m = 1; m < 64; m <<= 1) {
        p0 += __shfl_xor(p0, m, 64); p1 += __shfl_xor(p1, m, 64);
        p2 += __shfl_xor(p2, m, 64); p3 += __shfl_xor(p3, m, 64);
    }
    if (lane == 0) { pr[w][0] = p0; pr[w][1] = p1; pr[w][2] = p2; pr[w][3] = p3; }
    __syncthreads();
    if (t < 4) out[g * 4 + t] = pr[0][t] + pr[1][t] + pr[2][t] + pr[3][t] + b2[t];
}

// ---------------- launch ----------------

extern "C" void kernel_launch(void* const* d_in, const int* in_sizes, int n_in,
                              void* d_out, int out_size, void* d_ws, size_t ws_size,
                              hipStream_t stream)
{
    const float* x    = (const float*)d_in[0];
    const int*   ei   = (const int*)d_in[1];
    const int*   ptr  = (const int*)d_in[3];
    const float* Wl0  = (const float*)d_in[4];
    const float* bl0  = (const float*)d_in[5];
    const float* Wr0  = (const float*)d_in[6];
    const float* Wl   = (const float*)d_in[7];
    const float* bl   = (const float*)d_in[8];
    const float* Wr   = (const float*)d_in[9];
    const float* Wres = (const float*)d_in[10];
    const float* bres = (const float*)d_in[11];
    const float* lng  = (const float*)d_in[12];
    const float* lnb  = (const float*)d_in[13];
    const float* mW1  = (const float*)d_in[14];
    const float* mb1  = (const float*)d_in[15];
    const float* mg   = (const float*)d_in[16];
    const float* mbn  = (const float*)d_in[17];
    const float* mW2  = (const float*)d_in[18];
    const float* mb2  = (const float*)d_in[19];
    const float* rW1  = (const float*)d_in[20];
    const float* rb1  = (const float*)d_in[21];
    const float* rg   = (const float*)d_in[22];
    const float* rbn  = (const float*)d_in[23];
    const float* rW2  = (const float*)d_in[24];
    const float* rb2  = (const float*)d_in[25];
    float* out = (float*)d_out;

    int N = in_sizes[0] / 4;
    int E = in_sizes[1] / 2;
    int NG = in_sizes[3] - 1;
    int nchunk = (N + 255) / 256;
    int nblkm  = (N + 63) / 64;
    int NB     = (N + 255) >> BSHIFT;
    int nbh    = (E + 8191) / 8192;

    char* ws = (char*)d_ws;
    size_t o = 0;
    auto alloc = [&](size_t bytes) -> void* {
        void* p = ws + o;
        o += (bytes + 255) & ~(size_t)255;
        return p;
    };
    int*   off   = (int*)alloc((size_t)(N + 1) * 4);
    int*   btot  = (int*)alloc((size_t)NB * 4);
    int*   bbase = (int*)alloc((size_t)(NB + 1) * 4);
    int*   bcur  = (int*)alloc((size_t)NB * 4);
    int*   csr   = (int*)alloc((size_t)E * 4);
    int2*  pairs = (int2*)alloc((size_t)E * 8);
    float* ha    = (float*)alloc((size_t)N * 64 * 4);
    float* hb    = (float*)alloc((size_t)N * 64 * 4);
    float* aggws = (float*)alloc((size_t)N * 128 * 4);
    unsigned short* w1fh = (unsigned short*)alloc(16384 * 2);
    unsigned short* w1fl = (unsigned short*)alloc(16384 * 2);
    unsigned short* w2fh = (unsigned short*)alloc(16384 * 2);
    unsigned short* w2fl = (unsigned short*)alloc(16384 * 2);
    unsigned short* wsfh = (unsigned short*)alloc(36864 * 2);
    unsigned short* wsfl = (unsigned short*)alloc(36864 * 2);
    float* k12   = (float*)alloc(128 * 4);

    hipMemsetAsync(btot, 0, (size_t)NB * 4, stream);
    k_prep<<<6, 256, 0, stream>>>(mW1, mg, mbn, mW2, mb2, Wl, Wr,
                                  w1fh, w1fl, w2fh, w2fl, wsfh, wsfl, k12);
    k_bhist<<<nbh, 256, 0, stream>>>(ei, btot, E, NB);
    k_bscan<<<1, 256, 0, stream>>>(btot, bbase, bcur, NB, E);
    k_bscatter<<<nbh, 256, 0, stream>>>(ei, bcur, pairs, E, NB);
    k_bcsr<<<NB, 256, 0, stream>>>(pairs, bbase, csr, off, N, NB, E);

    k_layer0<<<nchunk, 256, 0, stream>>>(x, ha, off, csr, Wl0, bl0, Wr0, Wres, bres, lng, lnb, N);

    k_agg<<<2048, 256, 0, stream>>>(ha, aggws, off, csr, N);
    k_smm_m<<<nblkm, 256, 0, stream>>>(aggws, ha, hb, wsfh,               wsfl,               bl,       lng + 64,  lnb + 64,  N);
    k_agg<<<2048, 256, 0, stream>>>(hb, aggws, off, csr, N);
    k_smm_m<<<nblkm, 256, 0, stream>>>(aggws, hb, ha, wsfh + 24 * 64 * 8, wsfl + 24 * 64 * 8, bl + 64,  lng + 128, lnb + 128, N);
    k_agg<<<2048, 256, 0, stream>>>(ha, aggws, off, csr, N);
    k_smm_m<<<nblkm, 256, 0, stream>>>(aggws, ha, hb, wsfh + 48 * 64 * 8, wsfl + 48 * 64 * 8, bl + 128, lng + 192, lnb + 192, N);

    k_mlpm<<<nblkm, 256, 0, stream>>>(hb, ha, w1fh, w1fl, w2fh, w2fl, mb1, k12, N);
    k_readout<<<NG, 256, 0, stream>>>(ha, x, ptr, rW1, rb1, rg, rbn, rW2, rb2, out);
}

// Round 10
// 562.601 us; speedup vs baseline: 2.5034x; 1.0826x over previous
//
#include <hip/hip_runtime.h>
#include <math.h>

#define NEG_INF (-__builtin_inff())
#define BSHIFT 8                    // 256-node buckets
#define BCAP 6144                   // k_bcsr LDS pair capacity
#define CH 4096                     // edge chunk for bhist/bscatter (4 blocks/CU)

typedef __attribute__((ext_vector_type(8))) short short8;    // 8 bf16 = 4 VGPR
typedef __attribute__((ext_vector_type(4))) float f32x4;

__device__ __forceinline__ float silu_f(float y) {
    return y / (1.f + __expf(-y));
}

// bf16 round-to-nearest-even helpers for split-precision
__device__ __forceinline__ unsigned short f2bh(float x) {
    unsigned int u = __float_as_uint(x);
    u += 0x7fffu + ((u >> 16) & 1u);
    return (unsigned short)(u >> 16);
}
__device__ __forceinline__ float bh2f(unsigned short h) {
    return __uint_as_float(((unsigned int)h) << 16);
}

// ---------------- Bucketed CSR build ----------------

__global__ __launch_bounds__(256)
void k_bhist(const int* __restrict__ ei, int* __restrict__ btot, int E, int NB) {
    __shared__ int lh[512];
    int t = threadIdx.x;
    lh[t] = 0; lh[t + 256] = 0;
    __syncthreads();
    int base = blockIdx.x * CH;
    for (int i = t; i < CH; i += 256) {
        int e = base + i;
        if (e < E) atomicAdd(&lh[ei[E + e] >> BSHIFT], 1);
    }
    __syncthreads();
    if (lh[t]) atomicAdd(&btot[t], lh[t]);
    if (t + 256 < NB && lh[t + 256]) atomicAdd(&btot[t + 256], lh[t + 256]);
}

__global__ __launch_bounds__(256)
void k_bscan(const int* __restrict__ btot, int* __restrict__ bbase,
             int* __restrict__ bcur, int NB, int E) {
    __shared__ int s[512];
    int t = threadIdx.x;
    int v0 = (t < NB) ? btot[t] : 0;
    int v1 = (t + 256 < NB) ? btot[t + 256] : 0;
    s[t] = v0; s[t + 256] = v1;
    __syncthreads();
    for (int st = 1; st < 512; st <<= 1) {
        int a0 = (t >= st) ? s[t - st] : 0;
        int a1 = (t + 256 >= st) ? s[t + 256 - st] : 0;
        __syncthreads();
        s[t] += a0; s[t + 256] += a1;
        __syncthreads();
    }
    if (t < NB)       { bbase[t] = s[t] - v0;             bcur[t] = s[t] - v0; }
    if (t + 256 < NB) { bbase[t + 256] = s[t + 256] - v1; bcur[t + 256] = s[t + 256] - v1; }
    if (t == 0) bbase[NB] = E;
}

__global__ __launch_bounds__(256)
void k_bscatter(const int* __restrict__ ei, int* __restrict__ bcur,
                int2* __restrict__ pairs, int E, int NB) {
    __shared__ int2 sp[CH];                   // 32 KB staging
    __shared__ int lh[512], lsc[512], lcur[512], gb[512];
    int t = threadIdx.x;
    lh[t] = 0; lh[t + 256] = 0; lcur[t] = 0; lcur[t + 256] = 0;
    __syncthreads();
    int base = blockIdx.x * CH;
    for (int i = t; i < CH; i += 256) {
        int e = base + i;
        if (e < E) atomicAdd(&lh[ei[E + e] >> BSHIFT], 1);
    }
    __syncthreads();
    lsc[t] = lh[t]; lsc[t + 256] = lh[t + 256];
    __syncthreads();
    for (int st = 1; st < 512; st <<= 1) {
        int a0 = (t >= st) ? lsc[t - st] : 0;
        int a1 = (t + 256 >= st) ? lsc[t + 256 - st] : 0;
        __syncthreads();
        lsc[t] += a0; lsc[t + 256] += a1;
        __syncthreads();
    }
    for (int i = t; i < CH; i += 256) {
        int e = base + i;
        if (e < E) {
            int s = ei[e], d = ei[E + e];
            int b = d >> BSHIFT;
            int pos = lsc[b] - lh[b] + atomicAdd(&lcur[b], 1);
            sp[pos] = make_int2(s, d);
        }
    }
    __syncthreads();
    if (t < NB && lh[t]) gb[t] = atomicAdd(&bcur[t], lh[t]);
    if (t + 256 < NB && lh[t + 256]) gb[t + 256] = atomicAdd(&bcur[t + 256], lh[t + 256]);
    __syncthreads();
    int tot = lsc[511];
    for (int i = t; i < tot; i += 256) {
        int2 p = sp[i];
        int b = p.y >> BSHIFT;
        pairs[gb[b] + (i - (lsc[b] - lh[b]))] = p;
    }
}

__global__ __launch_bounds__(256)
void k_bcsr(const int2* __restrict__ pairs, const int* __restrict__ bbase,
            int* __restrict__ csr, int* __restrict__ off, int N, int NB, int E) {
    __shared__ int2 sp[BCAP];
    __shared__ int lh[256], lsc[256], lcur[256];
    int t = threadIdx.x;
    int b = blockIdx.x;
    int base = bbase[b];
    int m = bbase[b + 1] - base;
    int v0 = b << BSHIFT;
    lh[t] = 0; lcur[t] = 0;
    __syncthreads();
    bool fits = (m <= BCAP);
    for (int i = t; i < m; i += 256) {
        int2 p = pairs[base + i];
        if (fits) sp[i] = p;
        atomicAdd(&lh[p.y & 255], 1);
    }
    __syncthreads();
    int myv = lh[t];
    lsc[t] = myv;
    __syncthreads();
    for (int st = 1; st < 256; st <<= 1) {
        int a = (t >= st) ? lsc[t - st] : 0;
        __syncthreads();
        lsc[t] += a;
        __syncthreads();
    }
    int excl = lsc[t] - myv;
    __syncthreads();
    lsc[t] = excl;
    __syncthreads();
    int v = v0 + t;
    if (v < N) off[v] = base + excl;
    if (b == NB - 1 && t == 0) off[N] = E;
    for (int i = t; i < m; i += 256) {
        int2 p = fits ? sp[i] : pairs[base + i];
        int d = p.y & 255;
        int pos = lsc[d] + atomicAdd(&lcur[d], 1);
        csr[base + pos] = p.x;
    }
}

// ---------------- Prep: fragment-packed weights (bf16 hi/lo) ----------------
// b=0: mlp W1   b=1: mlp g*W2   b=2: k12   b=3..5: sage layer b-3

__global__ void k_prep(const float* __restrict__ mW1, const float* __restrict__ mg,
                       const float* __restrict__ mbn, const float* __restrict__ mW2,
                       const float* __restrict__ mb2,
                       const float* __restrict__ Wl, const float* __restrict__ Wr,
                       unsigned short* __restrict__ w1fh, unsigned short* __restrict__ w1fl,
                       unsigned short* __restrict__ w2fh, unsigned short* __restrict__ w2fl,
                       unsigned short* __restrict__ wsfh, unsigned short* __restrict__ wsfl,
                       float* __restrict__ k12)
{
    int b = blockIdx.x, t = threadIdx.x;
    if (b == 0) {
        for (int idx = t; idx < 2048; idx += 256) {
            int nt = idx >> 7, rem = idx & 127;
            int kc = rem >> 6, ln = rem & 63;
#pragma unroll
            for (int i = 0; i < 8; ++i) {
                int c = kc * 32 + (ln >> 4) * 8 + i;
                int j = nt * 16 + (ln & 15);
                float v = mW1[c * 256 + j];
                unsigned short hi = f2bh(v);
                w1fh[idx * 8 + i] = hi;
                w1fl[idx * 8 + i] = f2bh(v - bh2f(hi));
            }
        }
    } else if (b == 1) {
        for (int idx = t; idx < 2048; idx += 256) {
            int nt2 = idx >> 9, rem = idx & 511;
            int kc2 = rem >> 6, ln = rem & 63;
#pragma unroll
            for (int i = 0; i < 8; ++i) {
                int j = kc2 * 32 + (ln >> 4) * 8 + i;
                int o = nt2 * 16 + (ln & 15);
                float v = mg[j] * mW2[j * 64 + o];
                unsigned short hi = f2bh(v);
                w2fh[idx * 8 + i] = hi;
                w2fl[idx * 8 + i] = f2bh(v - bh2f(hi));
            }
        }
    } else if (b == 2 && t < 64) {
        float a1 = 0.f, a2 = 0.f;
        for (int j = 0; j < 256; ++j) {
            a1 += mbn[j] * mW2[j * 64 + t];
            a2 += mg[j]  * mW2[j * 64 + t];
        }
        k12[t] = a1 + mb2[t];
        k12[64 + t] = a2;
    } else if (b >= 3 && b < 6) {
        int l = b - 3;
        for (int idx = t; idx < 1536; idx += 256) {
            int tile = idx >> 6, ln = idx & 63;
            int nt = tile / 6, kc = tile % 6;
#pragma unroll
            for (int i = 0; i < 8; ++i) {
                int k = kc * 32 + (ln >> 4) * 8 + i;
                int o = nt * 16 + (ln & 15);
                float v = (k < 128) ? Wl[((l * 128) + k) * 64 + o]
                                    : Wr[((l * 64) + (k - 128)) * 64 + o];
                unsigned short hi = f2bh(v);
                wsfh[((l * 24 + tile) * 64 + ln) * 8 + i] = hi;
                wsfl[((l * 24 + tile) * 64 + ln) * 8 + i] = f2bh(v - bh2f(hi));
            }
        }
    }
}

// ---------------- Layer 0 (N_IN=4), one thread per node ----------------

__global__ __launch_bounds__(256, 4)
void k_layer0(const float* __restrict__ x, float* __restrict__ hout,
              const int* __restrict__ off, const int* __restrict__ csr,
              const float* __restrict__ Wl0, const float* __restrict__ bl0,
              const float* __restrict__ Wr0, const float* __restrict__ Wres,
              const float* __restrict__ bres, const float* __restrict__ lg,
              const float* __restrict__ lb, int N)
{
    __shared__ float sWl[512], sWr[256], sWres[256], sC[256];
    int t = threadIdx.x;
    sWl[t] = Wl0[t]; sWl[256 + t] = Wl0[256 + t];
    sWr[t] = Wr0[t];
    sWres[t] = Wres[t];
    if (t < 64) { sC[t] = bl0[t]; sC[64 + t] = bres[t]; sC[128 + t] = lg[t]; sC[192 + t] = lb[t]; }
    __syncthreads();
    int v = blockIdx.x * 256 + t;
    if (v >= N) return;
    const float4* X4 = reinterpret_cast<const float4*>(x);
    float4 xv = X4[v];
    int s0 = off[v], s1 = off[v + 1];
    float4 mx = {NEG_INF, NEG_INF, NEG_INF, NEG_INF};
    float4 sm = {0.f, 0.f, 0.f, 0.f};
    for (int e = s0; e < s1; e += 4) {
        int last = s1 - 1;
        int i0 = csr[e];
        int i1 = csr[min(e + 1, last)];
        int i2 = csr[min(e + 2, last)];
        int i3 = csr[min(e + 3, last)];
        float4 a0 = X4[i0], a1 = X4[i1], a2 = X4[i2], a3 = X4[i3];
        mx.x = fmaxf(fmaxf(fmaxf(mx.x, a0.x), fmaxf(a1.x, a2.x)), a3.x);
        mx.y = fmaxf(fmaxf(fmaxf(mx.y, a0.y), fmaxf(a1.y, a2.y)), a3.y);
        mx.z = fmaxf(fmaxf(fmaxf(mx.z, a0.z), fmaxf(a1.z, a2.z)), a3.z);
        mx.w = fmaxf(fmaxf(fmaxf(mx.w, a0.w), fmaxf(a1.w, a2.w)), a3.w);
        bool o1 = e + 1 < s1, o2 = e + 2 < s1, o3 = e + 3 < s1;
        sm.x += a0.x + (o1 ? a1.x : 0.f) + (o2 ? a2.x : 0.f) + (o3 ? a3.x : 0.f);
        sm.y += a0.y + (o1 ? a1.y : 0.f) + (o2 ? a2.y : 0.f) + (o3 ? a3.y : 0.f);
        sm.z += a0.z + (o1 ? a1.z : 0.f) + (o2 ? a2.z : 0.f) + (o3 ? a3.z : 0.f);
        sm.w += a0.w + (o1 ? a1.w : 0.f) + (o2 ? a2.w : 0.f) + (o3 ? a3.w : 0.f);
    }
    int deg = s1 - s0;
    if (deg == 0) { mx.x = 0.f; mx.y = 0.f; mx.z = 0.f; mx.w = 0.f; }
    float inv = 1.f / (float)max(deg, 1);
    float4 mn = {sm.x * inv, sm.y * inv, sm.z * inv, sm.w * inv};
    float a[64];
    float acc1 = 0.f, acc2 = 0.f;
#pragma unroll
    for (int k = 0; k < 64; ++k) {
        float tv = sC[k]
            + mx.x * sWl[k]       + mx.y * sWl[64 + k]  + mx.z * sWl[128 + k] + mx.w * sWl[192 + k]
            + mn.x * sWl[256 + k] + mn.y * sWl[320 + k] + mn.z * sWl[384 + k] + mn.w * sWl[448 + k]
            + xv.x * sWr[k]       + xv.y * sWr[64 + k]  + xv.z * sWr[128 + k] + xv.w * sWr[192 + k];
        a[k] = tv; acc1 += tv; acc2 += tv * tv;
    }
    float mu = acc1 * (1.f / 64.f);
    float var = acc2 * (1.f / 64.f) - mu * mu;
    float rs = rsqrtf(var + 1e-5f);
    float* orow = hout + (size_t)v * 64;
#pragma unroll
    for (int k = 0; k < 64; ++k) {
        float res = sC[64 + k] + xv.x * sWres[k] + xv.y * sWres[64 + k]
                  + xv.z * sWres[128 + k] + xv.w * sWres[192 + k];
        float y = (a[k] - mu) * rs * sC[128 + k] + sC[192 + k] + res;
        orow[k] = silu_f(y);
    }
}

// ---------------- k_agg: gather + aggregate, 16-deep unconditional + dup fix ----------------

__global__ __launch_bounds__(256, 8)
void k_agg(const float* __restrict__ hin, float* __restrict__ aggws,
           const int* __restrict__ off, const int* __restrict__ csr, int N)
{
    int lane = threadIdx.x & 63;
    int gw = (blockIdx.x * blockDim.x + threadIdx.x) >> 6;
    int nw = (gridDim.x * blockDim.x) >> 6;
    for (int v = gw; v < N; v += nw) {
        int s0 = off[v], s1 = off[v + 1];
        int deg = s1 - s0;
        float mx = NEG_INF, sm = 0.f;
        int npad = 0;
        for (int cb = s0; cb < s1; cb += 64) {
            int cdeg = min(64, s1 - cb);
            int idxv = csr[min(cb + lane, s1 - 1)];
            for (int b = 0; b < cdeg; b += 16) {
                float vv[16];
#pragma unroll
                for (int u = 0; u < 16; ++u) {
                    int iu = __builtin_amdgcn_readlane(idxv, b + u);  // b+u <= 63
                    vv[u] = hin[((size_t)iu << 6) + lane];
                }
#pragma unroll
                for (int u = 0; u < 16; ++u) { mx = fmaxf(mx, vv[u]); sm += vv[u]; }
            }
            npad += (((cdeg + 15) >> 4) << 4) - cdeg;   // dup lanes all clamp to csr[s1-1]
        }
        float mean;
        if (deg == 0) { mx = 0.f; mean = 0.f; }
        else {
            float hl = hin[((size_t)csr[s1 - 1] << 6) + lane];   // L1-hot (just gathered)
            mean = (sm - (float)npad * hl) / (float)deg;
        }
        aggws[((size_t)v << 7) + lane] = mx;
        aggws[((size_t)v << 7) + 64 + lane] = mean;
    }
}

// ---------------- k_smm_d: LDS-free MFMA SAGE matmul+LN+silu ----------------
// A-fragments loaded DIRECTLY from global: lane(quad,l15) of wave w holds
// row base+l15, k = kc*32+quad*8+i — 4 quads tile 128 B per row (coalesced).
// No LDS, no syncthreads. One wave = 16 nodes.

__global__ __launch_bounds__(256, 4)
void k_smm_d(const float* __restrict__ aggws, const float* __restrict__ hin,
             float* __restrict__ hout,
             const unsigned short* __restrict__ wfh, const unsigned short* __restrict__ wfl,
             const float* __restrict__ bl, const float* __restrict__ lg,
             const float* __restrict__ lb, int N)
{
    int t = threadIdx.x;
    int lane = t & 63, w = t >> 6, quad = lane >> 4, l15 = lane & 15;
    int nodebase = (blockIdx.x * 4 + w) * 16;
    if (nodebase >= N) return;
    int arow = min(nodebase + l15, N - 1);

    // ---- A fragments: 6 kc chunks of 8 fp32 -> bf16 hi/lo in registers ----
    short8 ah[6], al[6];
#pragma unroll
    for (int kc = 0; kc < 6; ++kc) {
        const float* src = (kc < 4)
            ? (aggws + ((size_t)arow << 7) + kc * 32 + quad * 8)
            : (hin + ((size_t)arow << 6) + (kc - 4) * 32 + quad * 8);
        float4 f0 = *(const float4*)(src);
        float4 f1 = *(const float4*)(src + 4);
        float vv[8] = {f0.x, f0.y, f0.z, f0.w, f1.x, f1.y, f1.z, f1.w};
#pragma unroll
        for (int i = 0; i < 8; ++i) {
            unsigned short hi = f2bh(vv[i]);
            ah[kc][i] = (short)hi;
            al[kc][i] = (short)f2bh(vv[i] - bh2f(hi));
        }
    }

    // ---- GEMM: K=192, nt 0..3, split-bf16 (3 products) ----
    f32x4 acc[4];
#pragma unroll
    for (int nt = 0; nt < 4; ++nt) acc[nt] = (f32x4){0.f, 0.f, 0.f, 0.f};
#pragma unroll
    for (int kc = 0; kc < 6; ++kc) {
#pragma unroll
        for (int nt = 0; nt < 4; ++nt) {
            int fo = ((nt * 6 + kc) * 64 + lane) * 8;
            short8 bh_ = *(const short8*)(wfh + fo);
            short8 bl_ = *(const short8*)(wfl + fo);
            acc[nt] = __builtin_amdgcn_mfma_f32_16x16x32_bf16(ah[kc], bh_, acc[nt], 0, 0, 0);
            acc[nt] = __builtin_amdgcn_mfma_f32_16x16x32_bf16(al[kc], bh_, acc[nt], 0, 0, 0);
            acc[nt] = __builtin_amdgcn_mfma_f32_16x16x32_bf16(ah[kc], bl_, acc[nt], 0, 0, 0);
        }
    }

    // ---- bias + quad-local LN + residual + silu + store ----
    float blv[4], gv[4], bv[4];
#pragma unroll
    for (int nt = 0; nt < 4; ++nt) {
        int ch = nt * 16 + l15;
        blv[nt] = bl[ch]; gv[nt] = lg[ch]; bv[nt] = lb[ch];
    }
    float ps[4], pq[4];
#pragma unroll
    for (int r = 0; r < 4; ++r) { ps[r] = 0.f; pq[r] = 0.f; }
#pragma unroll
    for (int nt = 0; nt < 4; ++nt)
#pragma unroll
        for (int r = 0; r < 4; ++r) {
            float tv = acc[nt][r] + blv[nt];
            acc[nt][r] = tv;
            ps[r] += tv; pq[r] += tv * tv;
        }
#pragma unroll
    for (int r = 0; r < 4; ++r) {
        float a = ps[r], b = pq[r];
#pragma unroll
        for (int m = 1; m < 16; m <<= 1) {
            a += __shfl_xor(a, m, 64);
            b += __shfl_xor(b, m, 64);
        }
        ps[r] = a; pq[r] = b;
    }
#pragma unroll
    for (int r = 0; r < 4; ++r) {
        int node = nodebase + quad * 4 + r;
        float mu = ps[r] * (1.f / 64.f);
        float var = pq[r] * (1.f / 64.f) - mu * mu;
        float rs = rsqrtf(var + 1e-5f);
        if (node < N) {
#pragma unroll
            for (int nt = 0; nt < 4; ++nt) {
                float hs = hin[(size_t)node * 64 + nt * 16 + l15];   // L2-hot
                float y = (acc[nt][r] - mu) * rs * gv[nt] + bv[nt] + hs;
                hout[(size_t)node * 64 + nt * 16 + l15] = silu_f(y);
            }
        }
    }
}

// ---------------- k_mlpm: MFMA MLP (round-7, proven) ----------------

__global__ __launch_bounds__(256, 2)
void k_mlpm(const float* __restrict__ hin, float* __restrict__ hout,
            const unsigned short* __restrict__ w1fh, const unsigned short* __restrict__ w1fl,
            const unsigned short* __restrict__ w2fh, const unsigned short* __restrict__ w2fl,
            const float* __restrict__ b1, const float* __restrict__ K12, int N)
{
    __shared__ __align__(16) char lds[70656];
    float* p1 = (float*)lds;
    float* p2 = (float*)(lds + 1024);
    unsigned short* hhi = (unsigned short*)(lds + 2048);
    unsigned short* hlo = (unsigned short*)(lds + 11264);
    unsigned int* spack = (unsigned int*)(lds + 2048);

    int t = threadIdx.x;
    int lane = t & 63, w = t >> 6, quad = lane >> 4, l15 = lane & 15;

    {
        int row = t >> 2, cq = (t & 3) * 16;
        int node0 = blockIdx.x * 64 + row;
        const float4* hr = (const float4*)(hin + (size_t)min(node0, N - 1) * 64 + cq);
        float v[16];
#pragma unroll
        for (int k = 0; k < 4; ++k) {
            float4 f = hr[k];
            v[4 * k] = f.x; v[4 * k + 1] = f.y; v[4 * k + 2] = f.z; v[4 * k + 3] = f.w;
        }
#pragma unroll
        for (int g = 0; g < 2; ++g) {
            short8 ph, pl;
#pragma unroll
            for (int i = 0; i < 8; ++i) {
                float x = v[g * 8 + i];
                unsigned short hi = f2bh(x);
                ph[i] = (short)hi;
                pl[i] = (short)f2bh(x - bh2f(hi));
            }
            int idx = row * 72 + cq + g * 8;
            *(short8*)(hhi + idx) = ph;
            *(short8*)(hlo + idx) = pl;
        }
    }
    __syncthreads();

    f32x4 acc[4][4];
#pragma unroll
    for (int mt = 0; mt < 4; ++mt)
#pragma unroll
        for (int nt = 0; nt < 4; ++nt)
            acc[mt][nt] = (f32x4){0.f, 0.f, 0.f, 0.f};
#pragma unroll
    for (int kc = 0; kc < 2; ++kc) {
        short8 ah[4], al[4];
#pragma unroll
        for (int mt = 0; mt < 4; ++mt) {
            int idx = (mt * 16 + l15) * 72 + kc * 32 + quad * 8;
            ah[mt] = *(const short8*)(hhi + idx);
            al[mt] = *(const short8*)(hlo + idx);
        }
#pragma unroll
        for (int nt = 0; nt < 4; ++nt) {
            int fo = (((w * 4 + nt) * 2 + kc) * 64 + lane) * 8;
            short8 bh_ = *(const short8*)(w1fh + fo);
            short8 bl_ = *(const short8*)(w1fl + fo);
#pragma unroll
            for (int mt = 0; mt < 4; ++mt) {
                acc[mt][nt] = __builtin_amdgcn_mfma_f32_16x16x32_bf16(ah[mt], bh_, acc[mt][nt], 0, 0, 0);
                acc[mt][nt] = __builtin_amdgcn_mfma_f32_16x16x32_bf16(al[mt], bh_, acc[mt][nt], 0, 0, 0);
                acc[mt][nt] = __builtin_amdgcn_mfma_f32_16x16x32_bf16(ah[mt], bl_, acc[mt][nt], 0, 0, 0);
            }
        }
    }

    float b1v[4];
#pragma unroll
    for (int nt = 0; nt < 4; ++nt) b1v[nt] = b1[(w * 4 + nt) * 16 + l15];
    float psum[4][4], psq[4][4];
#pragma unroll
    for (int mt = 0; mt < 4; ++mt)
#pragma unroll
        for (int r = 0; r < 4; ++r) { psum[mt][r] = 0.f; psq[mt][r] = 0.f; }
#pragma unroll
    for (int mt = 0; mt < 4; ++mt)
#pragma unroll
        for (int nt = 0; nt < 4; ++nt)
#pragma unroll
            for (int r = 0; r < 4; ++r) {
                float sv = silu_f(acc[mt][nt][r] + b1v[nt]);
                acc[mt][nt][r] = sv;
                psum[mt][r] += sv;
                psq[mt][r] += sv * sv;
            }
#pragma unroll
    for (int mt = 0; mt < 4; ++mt)
#pragma unroll
        for (int r = 0; r < 4; ++r) {
            float a = psum[mt][r], b = psq[mt][r];
#pragma unroll
            for (int m = 1; m < 16; m <<= 1) {
                a += __shfl_xor(a, m, 64);
                b += __shfl_xor(b, m, 64);
            }
            psum[mt][r] = a; psq[mt][r] = b;
        }
    if (l15 == 0) {
#pragma unroll
        for (int mt = 0; mt < 4; ++mt)
#pragma unroll
            for (int r = 0; r < 4; ++r) {
                int nl = mt * 16 + quad * 4 + r;
                p1[w * 64 + nl] = psum[mt][r];
                p2[w * 64 + nl] = psq[mt][r];
            }
    }
    __syncthreads();

#pragma unroll
    for (int mt = 0; mt < 4; ++mt)
#pragma unroll
        for (int nt = 0; nt < 4; ++nt)
#pragma unroll
            for (int r = 0; r < 4; ++r) {
                float sv = acc[mt][nt][r];
                unsigned short hi = f2bh(sv);
                unsigned short lo = f2bh(sv - bh2f(hi));
                spack[(mt * 16 + quad * 4 + r) * 268 + (w * 4 + nt) * 16 + l15] =
                    (((unsigned int)hi) << 16) | (unsigned int)lo;
            }
    __syncthreads();

    f32x4 acc2[4];
#pragma unroll
    for (int nt2 = 0; nt2 < 4; ++nt2) acc2[nt2] = (f32x4){0.f, 0.f, 0.f, 0.f};
#pragma unroll
    for (int kc2 = 0; kc2 < 8; ++kc2) {
        int base = (w * 16 + l15) * 268 + kc2 * 32 + quad * 8;
        uint4 q0 = *(const uint4*)(spack + base);
        uint4 q1 = *(const uint4*)(spack + base + 4);
        unsigned int vv[8] = {q0.x, q0.y, q0.z, q0.w, q1.x, q1.y, q1.z, q1.w};
        short8 ah, al;
#pragma unroll
        for (int i = 0; i < 8; ++i) {
            ah[i] = (short)(vv[i] >> 16);
            al[i] = (short)(vv[i] & 0xffffu);
        }
#pragma unroll
        for (int nt2 = 0; nt2 < 4; ++nt2) {
            int fo = ((nt2 * 8 + kc2) * 64 + lane) * 8;
            short8 bh_ = *(const short8*)(w2fh + fo);
            short8 bl_ = *(const short8*)(w2fl + fo);
            acc2[nt2] = __builtin_amdgcn_mfma_f32_16x16x32_bf16(ah, bh_, acc2[nt2], 0, 0, 0);
            acc2[nt2] = __builtin_amdgcn_mfma_f32_16x16x32_bf16(al, bh_, acc2[nt2], 0, 0, 0);
            acc2[nt2] = __builtin_amdgcn_mfma_f32_16x16x32_bf16(ah, bl_, acc2[nt2], 0, 0, 0);
        }
    }

    float k1v[4], k2v[4];
#pragma unroll
    for (int nt2 = 0; nt2 < 4; ++nt2) {
        k1v[nt2] = K12[nt2 * 16 + l15];
        k2v[nt2] = K12[64 + nt2 * 16 + l15];
    }
#pragma unroll
    for (int r = 0; r < 4; ++r) {
        int nl = w * 16 + quad * 4 + r;
        float s1 = p1[nl] + p1[64 + nl] + p1[128 + nl] + p1[192 + nl];
        float s2 = p2[nl] + p2[64 + nl] + p2[128 + nl] + p2[192 + nl];
        float mu = s1 * (1.f / 256.f);
        float var = s2 * (1.f / 256.f) - mu * mu;
        float rs = rsqrtf(var + 1e-5f);
        float rm = rs * mu;
        int node = blockIdx.x * 64 + nl;
        if (node < N) {
#pragma unroll
            for (int nt2 = 0; nt2 < 4; ++nt2)
                hout[(size_t)node * 64 + nt2 * 16 + l15] =
                    rs * acc2[nt2][r] + k1v[nt2] - rm * k2v[nt2];
        }
    }
}

// ---------------- Readout: block per graph ----------------

__global__ __launch_bounds__(256, 2)
void k_readout(const float* __restrict__ h2, const float* __restrict__ x,
               const int* __restrict__ ptr,
               const float* __restrict__ W1, const float* __restrict__ b1,
               const float* __restrict__ lg, const float* __restrict__ lb,
               const float* __restrict__ W2, const float* __restrict__ b2,
               float* __restrict__ out)
{
    __shared__ float f[196];
    __shared__ float sred[4][64];
    __shared__ float mred[4][64];
    __shared__ float lred[8];
    __shared__ float pr[4][4];
    int t = threadIdx.x, lane = t & 63, w = t >> 6;
    int g = blockIdx.x;
    int s0 = ptr[g], s1 = ptr[g + 1];
    float sm = 0.f, mx = NEG_INF;
    for (int r = s0 + w; r < s1; r += 4) {
        float v = h2[(size_t)r * 64 + lane];
        sm += v; mx = fmaxf(mx, v);
    }
    sred[w][lane] = sm; mred[w][lane] = mx;
    __syncthreads();
    if (w == 0) {
        float ssum = sred[0][lane] + sred[1][lane] + sred[2][lane] + sred[3][lane];
        float smax = fmaxf(fmaxf(mred[0][lane], mred[1][lane]),
                           fmaxf(mred[2][lane], mred[3][lane]));
        int cnt = s1 - s0;
        if (cnt == 0) smax = 0.f;
        f[lane] = ssum / (float)max(cnt, 1);
        f[64 + lane] = smax;
        f[128 + lane] = ssum;
    }
    if (t < 4) f[192 + t] = x[(size_t)s0 * 4 + t];
    __syncthreads();
    float o = b1[t];
    for (int c = 0; c < 196; ++c) o += f[c] * W1[c * 256 + t];
    o = silu_f(o);
    float s = o, s2v = o * o;
#pragma unroll
    for (int m = 1; m < 64; m <<= 1) { s += __shfl_xor(s, m, 64); s2v += __shfl_xor(s2v, m, 64); }
    if (lane == 0) { lred[w] = s; lred[4 + w] = s2v; }
    __syncthreads();
    float tot = lred[0] + lred[1] + lred[2] + lred[3];
    float tot2 = lred[4] + lred[5] + lred[6] + lred[7];
    float mu = tot * (1.f / 256.f);
    float var = tot2 * (1.f / 256.f) - mu * mu;
    float u = (o - mu) * rsqrtf(var + 1e-5f) * lg[t] + lb[t];
    float4 w2r = reinterpret_cast<const float4*>(W2)[t];
    float p0 = u * w2r.x, p1 = u * w2r.y, p2 = u * w2r.z, p3 = u * w2r.w;
#pragma unroll
    for (int m = 1; m < 64; m <<= 1) {
        p0 += __shfl_xor(p0, m, 64); p1 += __shfl_xor(p1, m, 64);
        p2 += __shfl_xor(p2, m, 64); p3 += __shfl_xor(p3, m, 64);
    }
    if (lane == 0) { pr[w][0] = p0; pr[w][1] = p1; pr[w][2] = p2; pr[w][3] = p3; }
    __syncthreads();
    if (t < 4) out[g * 4 + t] = pr[0][t] + pr[1][t] + pr[2][t] + pr[3][t] + b2[t];
}

// ---------------- launch ----------------

extern "C" void kernel_launch(void* const* d_in, const int* in_sizes, int n_in,
                              void* d_out, int out_size, void* d_ws, size_t ws_size,
                              hipStream_t stream)
{
    const float* x    = (const float*)d_in[0];
    const int*   ei   = (const int*)d_in[1];
    const int*   ptr  = (const int*)d_in[3];
    const float* Wl0  = (const float*)d_in[4];
    const float* bl0  = (const float*)d_in[5];
    const float* Wr0  = (const float*)d_in[6];
    const float* Wl   = (const float*)d_in[7];
    const float* bl   = (const float*)d_in[8];
    const float* Wr   = (const float*)d_in[9];
    const float* Wres = (const float*)d_in[10];
    const float* bres = (const float*)d_in[11];
    const float* lng  = (const float*)d_in[12];
    const float* lnb  = (const float*)d_in[13];
    const float* mW1  = (const float*)d_in[14];
    const float* mb1  = (const float*)d_in[15];
    const float* mg   = (const float*)d_in[16];
    const float* mbn  = (const float*)d_in[17];
    const float* mW2  = (const float*)d_in[18];
    const float* mb2  = (const float*)d_in[19];
    const float* rW1  = (const float*)d_in[20];
    const float* rb1  = (const float*)d_in[21];
    const float* rg   = (const float*)d_in[22];
    const float* rbn  = (const float*)d_in[23];
    const float* rW2  = (const float*)d_in[24];
    const float* rb2  = (const float*)d_in[25];
    float* out = (float*)d_out;

    int N = in_sizes[0] / 4;
    int E = in_sizes[1] / 2;
    int NG = in_sizes[3] - 1;
    int nchunk = (N + 255) / 256;
    int nblkm  = (N + 63) / 64;
    int NB     = (N + 255) >> BSHIFT;
    int nbh    = (E + CH - 1) / CH;

    char* ws = (char*)d_ws;
    size_t o = 0;
    auto alloc = [&](size_t bytes) -> void* {
        void* p = ws + o;
        o += (bytes + 255) & ~(size_t)255;
        return p;
    };
    int*   off   = (int*)alloc((size_t)(N + 1) * 4);
    int*   btot  = (int*)alloc((size_t)NB * 4);
    int*   bbase = (int*)alloc((size_t)(NB + 1) * 4);
    int*   bcur  = (int*)alloc((size_t)NB * 4);
    int*   csr   = (int*)alloc((size_t)E * 4);
    int2*  pairs = (int2*)alloc((size_t)E * 8);
    float* ha    = (float*)alloc((size_t)N * 64 * 4);
    float* hb    = (float*)alloc((size_t)N * 64 * 4);
    float* aggws = (float*)alloc((size_t)N * 128 * 4);
    unsigned short* w1fh = (unsigned short*)alloc(16384 * 2);
    unsigned short* w1fl = (unsigned short*)alloc(16384 * 2);
    unsigned short* w2fh = (unsigned short*)alloc(16384 * 2);
    unsigned short* w2fl = (unsigned short*)alloc(16384 * 2);
    unsigned short* wsfh = (unsigned short*)alloc(36864 * 2);
    unsigned short* wsfl = (unsigned short*)alloc(36864 * 2);
    float* k12   = (float*)alloc(128 * 4);

    hipMemsetAsync(btot, 0, (size_t)NB * 4, stream);
    k_prep<<<6, 256, 0, stream>>>(mW1, mg, mbn, mW2, mb2, Wl, Wr,
                                  w1fh, w1fl, w2fh, w2fl, wsfh, wsfl, k12);
    k_bhist<<<nbh, 256, 0, stream>>>(ei, btot, E, NB);
    k_bscan<<<1, 256, 0, stream>>>(btot, bbase, bcur, NB, E);
    k_bscatter<<<nbh, 256, 0, stream>>>(ei, bcur, pairs, E, NB);
    k_bcsr<<<NB, 256, 0, stream>>>(pairs, bbase, csr, off, N, NB, E);

    k_layer0<<<nchunk, 256, 0, stream>>>(x, ha, off, csr, Wl0, bl0, Wr0, Wres, bres, lng, lnb, N);

    k_agg<<<2048, 256, 0, stream>>>(ha, aggws, off, csr, N);
    k_smm_d<<<nblkm, 256, 0, stream>>>(aggws, ha, hb, wsfh,               wsfl,               bl,       lng + 64,  lnb + 64,  N);
    k_agg<<<2048, 256, 0, stream>>>(hb, aggws, off, csr, N);
    k_smm_d<<<nblkm, 256, 0, stream>>>(aggws, hb, ha, wsfh + 24 * 64 * 8, wsfl + 24 * 64 * 8, bl + 64,  lng + 128, lnb + 128, N);
    k_agg<<<2048, 256, 0, stream>>>(ha, aggws, off, csr, N);
    k_smm_d<<<nblkm, 256, 0, stream>>>(aggws, ha, hb, wsfh + 48 * 64 * 8, wsfl + 48 * 64 * 8, bl + 128, lng + 192, lnb + 192, N);

    k_mlpm<<<nblkm, 256, 0, stream>>>(hb, ha, w1fh, w1fl, w2fh, w2fl, mb1, k12, N);
    k_readout<<<NG, 256, 0, stream>>>(ha, x, ptr, rW1, rb1, rg, rbn, rW2, rb2, out);
}